// Round 5
// baseline (278.683 us; speedup 1.0000x reference)
//
#include <hip/hip_runtime.h>
#include <hip/hip_bf16.h>

#define NN 3072
#define CCC 16
#define HH 128
#define KTOP 4
#define NCLS 455   // C(15,3)
#define NUP 120    // 15 singles + 105 pairs
#define EPSF 1e-5f

// ---------------- ws layout (float offsets) ----------------
#define OFF_F       0
#define SZ_F        (16*NCLS*HH)            // 931840
#define OFF_CNT     (OFF_F + SZ_F)          // class counts (float), 7280
#define SZ_CNT      (16*NCLS)
#define OFF_SUMS    (OFF_CNT + SZ_CNT)      // sumHc[16], sumSq[16]
#define SZ_SUMS     32
#define OFF_NCNT    (OFF_SUMS + SZ_SUMS)    // int nodeCnt[16*16] (64B-padded per counter)
#define SZ_NCNT     256
#define OFF_LOGITS  (OFF_NCNT + SZ_NCNT)
#define SZ_LOGITS   (NN*CCC)
#define OFF_COLS    (OFF_LOGITS + SZ_LOGITS)   // int, per (n,slot)
#define SZ_E        (NN*KTOP)
#define OFF_RANKS   (OFF_COLS + SZ_E)          // int
#define OFF_FISEL   (OFF_RANKS + SZ_E)         // float
#define OFF_NLIST   (OFF_FISEL + SZ_E)         // int, 16*NN
#define SZ_NLIST    (16*NN)
#define OFF_AGG     (OFF_NLIST + SZ_NLIST)     // 16*455*128 (reused in-place for AggWl)
#define OFF_HC      (OFF_AGG + SZ_F)           // 12288*128
#define SZ_HC       (NN*KTOP*HH)

__device__ __forceinline__ int C2i(int x){ return x*(x-1)/2; }
__device__ __forceinline__ int C3i(int x){ return x*(x-1)*(x-2)/6; }

// ================= stage A: z=relu(X@W1^T+b1); LN; logit=zn.W2+b2 =================
#define MT 64
#define KC 32
__global__ __launch_bounds__(256) void k_logits(const float* __restrict__ X,
    const float* __restrict__ W1, const float* __restrict__ b1,
    const float* __restrict__ ln_g, const float* __restrict__ ln_b,
    const float* __restrict__ W2, const float* __restrict__ b2,
    float* __restrict__ logits){
  __shared__ float xs[MT][132];
  __shared__ float wch[KC][128];
  int t = threadIdx.x;
  int tr = t >> 4;
  int tc = t & 15;
  int base = blockIdx.x * MT;

  for (int idx = t; idx < MT*32; idx += 256){
    int r = idx >> 5, c4 = (idx & 31) << 2;
    float4 v = *(const float4*)(X + (size_t)(base + r)*HH + c4);
    xs[r][c4] = v.x; xs[r][c4+1] = v.y; xs[r][c4+2] = v.z; xs[r][c4+3] = v.w;
  }

  float acc[4][8];
  #pragma unroll
  for (int i=0;i<4;++i)
    #pragma unroll
    for (int j=0;j<8;++j) acc[i][j]=0.f;

  for (int k0 = 0; k0 < HH; k0 += KC){
    __syncthreads();
    {
      int o = t & 127, half = t >> 7;
      #pragma unroll
      for (int q = 0; q < 2; ++q){
        int kk = half*16 + q*8;
        float4 a = *(const float4*)(W1 + o*HH + k0 + kk);
        float4 b = *(const float4*)(W1 + o*HH + k0 + kk + 4);
        wch[kk+0][o]=a.x; wch[kk+1][o]=a.y; wch[kk+2][o]=a.z; wch[kk+3][o]=a.w;
        wch[kk+4][o]=b.x; wch[kk+5][o]=b.y; wch[kk+6][o]=b.z; wch[kk+7][o]=b.w;
      }
    }
    __syncthreads();
    const float* x0 = &xs[tr*4+0][k0];
    const float* x1 = &xs[tr*4+1][k0];
    const float* x2 = &xs[tr*4+2][k0];
    const float* x3 = &xs[tr*4+3][k0];
    #pragma unroll 8
    for (int k = 0; k < KC; ++k){
      float a0 = x0[k], a1 = x1[k], a2 = x2[k], a3 = x3[k];
      float4 wA = *(const float4*)&wch[k][tc*4];
      float4 wB = *(const float4*)&wch[k][64 + tc*4];
      float w[8] = {wA.x,wA.y,wA.z,wA.w,wB.x,wB.y,wB.z,wB.w};
      #pragma unroll
      for (int j=0;j<8;++j){
        acc[0][j] += a0*w[j]; acc[1][j] += a1*w[j];
        acc[2][j] += a2*w[j]; acc[3][j] += a3*w[j];
      }
    }
  }

  float4 bA = *(const float4*)(b1 + tc*4),  bB = *(const float4*)(b1 + 64 + tc*4);
  float4 gA = *(const float4*)(ln_g + tc*4), gB = *(const float4*)(ln_g + 64 + tc*4);
  float4 lA = *(const float4*)(ln_b + tc*4), lB = *(const float4*)(ln_b + 64 + tc*4);
  float4 wA2 = *(const float4*)(W2 + tc*4),  wB2 = *(const float4*)(W2 + 64 + tc*4);
  float bv[8] = {bA.x,bA.y,bA.z,bA.w,bB.x,bB.y,bB.z,bB.w};
  float gv[8] = {gA.x,gA.y,gA.z,gA.w,gB.x,gB.y,gB.z,gB.w};
  float lv[8] = {lA.x,lA.y,lA.z,lA.w,lB.x,lB.y,lB.z,lB.w};
  float wv[8] = {wA2.x,wA2.y,wA2.z,wA2.w,wB2.x,wB2.y,wB2.z,wB2.w};
  float b2v = b2[0];
  #pragma unroll
  for (int i=0;i<4;++i){
    float s1=0.f, s2=0.f;
    #pragma unroll
    for (int j=0;j<8;++j){
      float z = acc[i][j] + bv[j]; z = z>0.f?z:0.f;
      acc[i][j] = z; s1 += z; s2 += z*z;
    }
    #pragma unroll
    for (int m=1;m<16;m<<=1){ s1 += __shfl_xor(s1,m); s2 += __shfl_xor(s2,m); }
    float mu = s1/(float)HH;
    float var = s2/(float)HH - mu*mu;
    float rs = 1.0f/sqrtf(var+EPSF);
    float s3 = 0.f;
    #pragma unroll
    for (int j=0;j<8;++j){
      float zn = (acc[i][j]-mu)*rs*gv[j] + lv[j];
      s3 += zn*wv[j];
    }
    #pragma unroll
    for (int m=1;m<16;m<<=1) s3 += __shfl_xor(s3,m);
    if (tc == 0) logits[base + tr*4 + i] = s3 + b2v;
  }
}

// ================= stage B: softmax fi, top-4, class ranks, node lists =================
__global__ __launch_bounds__(256) void k_topk(const float* __restrict__ logits,
    int* __restrict__ cols, int* __restrict__ ranks, float* __restrict__ fiSel,
    int* __restrict__ nodeCnt, int* __restrict__ nodeList){
  __shared__ int lcnt[CCC];
  __shared__ int lbase[CCC];
  int t = threadIdx.x;
  if (t < CCC) lcnt[t] = 0;
  __syncthreads();
  int n = blockIdx.x*256 + t;
  float l[CCC];
  #pragma unroll
  for (int c=0;c<CCC;++c) l[c] = logits[n*CCC+c];
  unsigned mask = 0;
  #pragma unroll
  for (int k=0;k<KTOP;++k){
    float best = -3e38f; int bi = 0;
    #pragma unroll
    for (int c=0;c<CCC;++c){
      bool taken = (mask>>c)&1u;
      if (!taken && l[c] > best){ best = l[c]; bi = c; }
    }
    mask |= 1u<<bi;
  }
  float m = -3e38f;
  #pragma unroll
  for (int c=0;c<CCC;++c) m = l[c]>m ? l[c] : m;
  float s = 0.f;
  #pragma unroll
  for (int c=0;c<CCC;++c) s += expf(l[c]-m);
  float inv = 1.0f/s;
  int mycis[KTOP], mypos[KTOP];
  unsigned m2 = mask;
  for (int j=0;j<KTOP;++j){
    int ci = __ffs(m2)-1; m2 &= m2-1u;
    unsigned rest = mask & ~(1u<<ci);
    int v[3]; unsigned r2 = rest;
    #pragma unroll
    for (int q=0;q<3;++q){ int col = __ffs(r2)-1; r2 &= r2-1u; v[q] = col - (col>ci ? 1:0); }
    int rank = C3i(v[2]) + C2i(v[1]) + v[0];
    int e4 = n*KTOP + j;
    cols[e4] = ci; ranks[e4] = rank;
    fiSel[e4] = expf(l[ci]-m)*inv;
    mycis[j] = ci;
    mypos[j] = atomicAdd(&lcnt[ci], 1);
  }
  __syncthreads();
  if (t < CCC) lbase[t] = atomicAdd(&nodeCnt[t*16], lcnt[t]);
  __syncthreads();
  #pragma unroll
  for (int j=0;j<KTOP;++j){
    int ci = mycis[j];
    nodeList[ci*NN + lbase[ci] + mypos[j]] = n*KTOP + j;
  }
}

// ================= stage C: class feature sums (LDS-resident, no global atomics) =======
// grid (4 col-quarters, 16 ci), 256 threads. F[455][32] lives in LDS (58 KB).
__global__ __launch_bounds__(256) void k_accF(const float* __restrict__ X,
    const int* __restrict__ ranks, const float* __restrict__ fiSel,
    const int* __restrict__ nodeCnt, const int* __restrict__ nodeList,
    float* __restrict__ F, float* __restrict__ cnt){
  int hb = blockIdx.x;       // col quarter 0..3
  int ci = blockIdx.y;
  int t  = threadIdx.x;
  __shared__ float Fl[NCLS*32];
  __shared__ float cntL[NCLS];
  __shared__ int   eN[64];
  __shared__ int   eR[64];
  __shared__ float eF[64];
  for (int i=t;i<NCLS*32;i+=256) Fl[i]=0.f;
  if (hb==0) for (int i=t;i<NCLS;i+=256) cntL[i]=0.f;
  int cntc = nodeCnt[ci*16];
  __syncthreads();
  for (int b0=0;b0<cntc;b0+=64){
    int nb = cntc-b0; if (nb>64) nb=64;
    if (t<nb){
      int e = nodeList[ci*NN + b0 + t];
      int rk = ranks[e];
      eN[t] = e>>2; eR[t] = rk; eF[t] = fiSel[e];
      if (hb==0) atomicAdd(&cntL[rk], 1.0f);
    }
    __syncthreads();
    int col = t & 31;
    for (int j = t>>5; j<nb; j+=8){
      float v = X[((size_t)eN[j]*CCC+ci)*HH + hb*32 + col] * eF[j];
      atomicAdd(&Fl[eR[j]*32 + col], v);
    }
    __syncthreads();
  }
  for (int i=t;i<NCLS*32;i+=256){
    int r = i>>5, col = i&31;
    F[((size_t)ci*NCLS+r)*HH + hb*32 + col] = Fl[i];
  }
  if (hb==0) for (int i=t;i<NCLS;i+=256) cnt[ci*NCLS+i] = cntL[i];
}

// ====== stage D (fused): pairs + singles + degrees + inclusion-exclusion agg ======
// grid (4 col-quarters, 16 ci), 256 threads. P/U in LDS; degrees from
// count-level inclusion-exclusion (no 455x455 scan).
__global__ __launch_bounds__(256) void k_graphagg(const float* __restrict__ F,
    const float* __restrict__ cnt, float* __restrict__ agg){
  int hb = blockIdx.x, ci = blockIdx.y, t = threadIdx.x;
  __shared__ float P[105*32];
  __shared__ float U[15*32];
  __shared__ float cntl[NCLS];
  __shared__ float invd[NCLS];
  __shared__ int   abcs[NCLS];   // a | b<<5 | c<<10
  __shared__ int   prs[NCLS];    // pab | pac<<10 | pbc<<20
  __shared__ int   pp[105];      // pa | pb<<8
  __shared__ float PcS[105];
  __shared__ float UcS[15];
  const float* Fc = F + (size_t)ci*NCLS*HH + hb*32;

  for (int r=t; r<NCLS; r+=256){
    cntl[r] = cnt[ci*NCLS+r];
    int c=2; while (c<14 && C3i(c+1)<=r) c++;
    int rem = r - C3i(c);
    int b=1; while (b<c-1 && C2i(b+1)<=rem) b++;
    int a = rem - C2i(b);
    abcs[r] = a | (b<<5) | (c<<10);
    prs[r] = (C2i(b)+a) | ((C2i(c)+a)<<10) | ((C2i(c)+b)<<20);
  }
  if (t<105){
    int pb=1; while (pb<14 && C2i(pb+1)<=t) pb++;
    pp[t] = (t - C2i(pb)) | (pb<<8);
  }
  __syncthreads();
  // count-level pair sums
  if (t<105){
    int pa = pp[t]&255, pb = pp[t]>>8;
    float s=0.f;
    #pragma unroll
    for (int z=0;z<15;++z){
      if (z==pa||z==pb) continue;
      int lo,mid,hi;
      if (z<pa){lo=z;mid=pa;hi=pb;} else if (z<pb){lo=pa;mid=z;hi=pb;} else {lo=pa;mid=pb;hi=z;}
      s += cntl[C3i(hi)+C2i(mid)+lo];
    }
    PcS[t]=s;
  }
  __syncthreads();
  if (t<15){
    float s=0.f;
    #pragma unroll
    for (int y=0;y<15;++y){
      if (y==t) continue;
      int lo = t<y?t:y, hi = t<y?y:t;
      s += PcS[C2i(hi)+lo];
    }
    UcS[t]=0.5f*s;
  }
  __syncthreads();
  for (int r=t;r<NCLS;r+=256){
    int v1=abcs[r]; int a=v1&31,b=(v1>>5)&31,c=(v1>>10)&31;
    int v2=prs[r];  int pab=v2&1023,pac=(v2>>10)&1023,pbc=(v2>>20)&1023;
    float deg = UcS[a]+UcS[b]+UcS[c]-PcS[pab]-PcS[pac]-PcS[pbc]+cntl[r];
    invd[r] = 1.0f/fmaxf(deg,1.0f);
  }
  // vector pair sums (13 direct summands each, from global F slice)
  for (int idx=t; idx<105*32; idx+=256){
    int p = idx>>5, col = idx&31;
    int pa = pp[p]&255, pb = pp[p]>>8;
    float s=0.f;
    #pragma unroll
    for (int z=0;z<15;++z){
      if (z==pa||z==pb) continue;
      int lo,mid,hi;
      if (z<pa){lo=z;mid=pa;hi=pb;} else if (z<pb){lo=pa;mid=z;hi=pb;} else {lo=pa;mid=pb;hi=z;}
      s += Fc[(size_t)(C3i(hi)+C2i(mid)+lo)*HH + col];
    }
    P[idx]=s;
  }
  __syncthreads();
  // vector singles
  for (int idx=t; idx<15*32; idx+=256){
    int x = idx>>5, col = idx&31;
    float s=0.f;
    #pragma unroll
    for (int y=0;y<15;++y){
      if (y==x) continue;
      int lo = x<y?x:y, hi = x<y?y:x;
      s += P[(C2i(hi)+lo)*32 + col];
    }
    U[idx]=0.5f*s;
  }
  __syncthreads();
  // agg via inclusion-exclusion
  for (int idx=t; idx<NCLS*32; idx+=256){
    int r = idx>>5, col = idx&31;
    int v1=abcs[r]; int a=v1&31,b=(v1>>5)&31,c=(v1>>10)&31;
    int v2=prs[r];  int pab=v2&1023,pac=(v2>>10)&1023,pbc=(v2>>20)&1023;
    float v = U[a*32+col]+U[b*32+col]+U[c*32+col]
            - P[pab*32+col]-P[pac*32+col]-P[pbc*32+col]
            + Fc[(size_t)r*HH + col];
    agg[(size_t)ci*NCLS*HH + (size_t)r*HH + hb*32 + col] = v*invd[r];
  }
}

// ================= stage E1: AggWl = Agg @ Wl^T + bl (per class, in-place) =================
__global__ __launch_bounds__(256) void k_aggwl(float* __restrict__ agg,
    const float* __restrict__ Wl, const float* __restrict__ bl){
  __shared__ float xs[MT][132];
  __shared__ float wch[KC][128];
  int t = threadIdx.x;
  int tr = t >> 4, tc = t & 15;
  int ci = blockIdx.y;
  int base = blockIdx.x * MT;

  float* A = agg + (size_t)ci*NCLS*HH;
  for (int idx = t; idx < MT*32; idx += 256){
    int r = idx >> 5, c4 = (idx & 31) << 2;
    int rg = base + r; if (rg > NCLS-1) rg = NCLS-1;
    float4 v = *(const float4*)(A + (size_t)rg*HH + c4);
    xs[r][c4] = v.x; xs[r][c4+1] = v.y; xs[r][c4+2] = v.z; xs[r][c4+3] = v.w;
  }

  float acc[4][8];
  #pragma unroll
  for (int i=0;i<4;++i)
    #pragma unroll
    for (int j=0;j<8;++j) acc[i][j]=0.f;

  const float* W = Wl + (size_t)ci*HH*HH;
  for (int k0 = 0; k0 < HH; k0 += KC){
    __syncthreads();
    {
      int o = t & 127, half = t >> 7;
      #pragma unroll
      for (int q = 0; q < 2; ++q){
        int kk = half*16 + q*8;
        float4 a = *(const float4*)(W + o*HH + k0 + kk);
        float4 b = *(const float4*)(W + o*HH + k0 + kk + 4);
        wch[kk+0][o]=a.x; wch[kk+1][o]=a.y; wch[kk+2][o]=a.z; wch[kk+3][o]=a.w;
        wch[kk+4][o]=b.x; wch[kk+5][o]=b.y; wch[kk+6][o]=b.z; wch[kk+7][o]=b.w;
      }
    }
    __syncthreads();
    const float* x0 = &xs[tr*4+0][k0];
    const float* x1 = &xs[tr*4+1][k0];
    const float* x2 = &xs[tr*4+2][k0];
    const float* x3 = &xs[tr*4+3][k0];
    #pragma unroll 8
    for (int k = 0; k < KC; ++k){
      float a0 = x0[k], a1 = x1[k], a2 = x2[k], a3 = x3[k];
      float4 wA = *(const float4*)&wch[k][tc*4];
      float4 wB = *(const float4*)&wch[k][64 + tc*4];
      float w[8] = {wA.x,wA.y,wA.z,wA.w,wB.x,wB.y,wB.z,wB.w};
      #pragma unroll
      for (int j=0;j<8;++j){
        acc[0][j] += a0*w[j]; acc[1][j] += a1*w[j];
        acc[2][j] += a2*w[j]; acc[3][j] += a3*w[j];
      }
    }
  }
  float4 blA = *(const float4*)(bl + ci*HH + tc*4);
  float4 blB = *(const float4*)(bl + ci*HH + 64 + tc*4);
  #pragma unroll
  for (int i=0;i<4;++i){
    int row = base + tr*4 + i;
    if (row < NCLS){
      float4 oA = { acc[i][0]+blA.x, acc[i][1]+blA.y, acc[i][2]+blA.z, acc[i][3]+blA.w };
      float4 oB = { acc[i][4]+blB.x, acc[i][5]+blB.y, acc[i][6]+blB.z, acc[i][7]+blB.w };
      *(float4*)(A + (size_t)row*HH + tc*4) = oA;
      *(float4*)(A + (size_t)row*HH + 64 + tc*4) = oB;
    }
  }
}

// ================= stage E2: hc = relu(AggWl[class] + fi*X @ Wr^T) per node =================
__global__ __launch_bounds__(256) void k_hc2(const float* __restrict__ X,
    const float* __restrict__ Wr,
    const int* __restrict__ ranks, const float* __restrict__ fiSel,
    const int* __restrict__ nodeCnt, const int* __restrict__ nodeList,
    const float* __restrict__ aggwl, float* __restrict__ hcBuf, float* __restrict__ sums){
  int ci = blockIdx.y;
  int cntc = nodeCnt[ci*16];
  int base = blockIdx.x * MT;
  if (base >= cntc) return;
  __shared__ float xs[MT][132];
  __shared__ float wch[KC][128];
  __shared__ int   es[MT];
  __shared__ float fis[MT];
  __shared__ int   rks[MT];
  __shared__ float rb[8];
  int t = threadIdx.x;
  int tr = t >> 4, tc = t & 15;
  if (t < MT){
    int p = base + t;
    if (p < cntc){
      int e = nodeList[ci*NN + p];
      es[t] = e; fis[t] = fiSel[e]; rks[t] = ranks[e];
    } else { es[t] = -1; fis[t] = 0.f; rks[t] = 0; }
  }
  __syncthreads();
  for (int idx = t; idx < MT*32; idx += 256){
    int r = idx >> 5, c4 = (idx & 31) << 2;
    int e = es[r];
    if (e >= 0){
      int n = e >> 2;
      float fi = fis[r];
      float4 v = *(const float4*)(X + (size_t)(n*CCC+ci)*HH + c4);
      xs[r][c4] = v.x*fi; xs[r][c4+1] = v.y*fi; xs[r][c4+2] = v.z*fi; xs[r][c4+3] = v.w*fi;
    } else {
      xs[r][c4]=0.f; xs[r][c4+1]=0.f; xs[r][c4+2]=0.f; xs[r][c4+3]=0.f;
    }
  }

  float acc[4][8];
  #pragma unroll
  for (int i=0;i<4;++i)
    #pragma unroll
    for (int j=0;j<8;++j) acc[i][j]=0.f;

  const float* W = Wr + (size_t)ci*HH*HH;
  for (int k0 = 0; k0 < HH; k0 += KC){
    __syncthreads();
    {
      int o = t & 127, half = t >> 7;
      #pragma unroll
      for (int q = 0; q < 2; ++q){
        int kk = half*16 + q*8;
        float4 a = *(const float4*)(W + o*HH + k0 + kk);
        float4 b = *(const float4*)(W + o*HH + k0 + kk + 4);
        wch[kk+0][o]=a.x; wch[kk+1][o]=a.y; wch[kk+2][o]=a.z; wch[kk+3][o]=a.w;
        wch[kk+4][o]=b.x; wch[kk+5][o]=b.y; wch[kk+6][o]=b.z; wch[kk+7][o]=b.w;
      }
    }
    __syncthreads();
    const float* x0 = &xs[tr*4+0][k0];
    const float* x1 = &xs[tr*4+1][k0];
    const float* x2 = &xs[tr*4+2][k0];
    const float* x3 = &xs[tr*4+3][k0];
    #pragma unroll 8
    for (int k = 0; k < KC; ++k){
      float a0 = x0[k], a1 = x1[k], a2 = x2[k], a3 = x3[k];
      float4 wA = *(const float4*)&wch[k][tc*4];
      float4 wB = *(const float4*)&wch[k][64 + tc*4];
      float w[8] = {wA.x,wA.y,wA.z,wA.w,wB.x,wB.y,wB.z,wB.w};
      #pragma unroll
      for (int j=0;j<8;++j){
        acc[0][j] += a0*w[j]; acc[1][j] += a1*w[j];
        acc[2][j] += a2*w[j]; acc[3][j] += a3*w[j];
      }
    }
  }

  float s1 = 0.f, s2 = 0.f;
  #pragma unroll
  for (int i=0;i<4;++i){
    int r = tr*4 + i;
    int e = es[r];
    if (e >= 0){
      int rank = rks[r];
      const float* G = aggwl + (size_t)(ci*NCLS + rank)*HH;
      float4 gA = *(const float4*)(G + tc*4);
      float4 gB = *(const float4*)(G + 64 + tc*4);
      float g[8] = {gA.x,gA.y,gA.z,gA.w,gB.x,gB.y,gB.z,gB.w};
      float hc[8];
      #pragma unroll
      for (int j=0;j<8;++j){
        float v = acc[i][j] + g[j];
        v = v>0.f ? v : 0.f;
        hc[j] = v; s1 += v; s2 += v*v;
      }
      float4 oA = {hc[0],hc[1],hc[2],hc[3]};
      float4 oB = {hc[4],hc[5],hc[6],hc[7]};
      *(float4*)(hcBuf + (size_t)e*HH + tc*4) = oA;
      *(float4*)(hcBuf + (size_t)e*HH + 64 + tc*4) = oB;
    }
  }
  #pragma unroll
  for (int m=1;m<64;m<<=1){ s1 += __shfl_xor(s1,m); s2 += __shfl_xor(s2,m); }
  int wid = t >> 6;
  if ((t&63)==0){ rb[wid] = s1; rb[4+wid] = s2; }
  __syncthreads();
  if (t==0){
    atomicAdd(&sums[ci],    rb[0]+rb[1]+rb[2]+rb[3]);
    atomicAdd(&sums[16+ci], rb[4]+rb[5]+rb[6]+rb[7]);
  }
}

// ================= stage F: masked mean/var normalize, write output =================
__global__ __launch_bounds__(256) void k_out(const float* __restrict__ hcBuf,
    const int* __restrict__ cols, const int* __restrict__ nodeCnt,
    const float* __restrict__ sums, float* __restrict__ out){
  int idx = blockIdx.x*256 + threadIdx.x;
  int e = idx >> 7;
  int ci = cols[e];
  float cntf = (float)nodeCnt[ci*16];
  float nel = fmaxf(cntf * (float)HH, 1.0f);
  float mu = sums[ci]/nel;
  float var = sums[16+ci]/nel - mu*mu;
  out[idx] = (hcBuf[idx]-mu)/sqrtf(var+EPSF);
}

extern "C" void kernel_launch(void* const* d_in, const int* in_sizes, int n_in,
                              void* d_out, int out_size, void* d_ws, size_t ws_size,
                              hipStream_t stream){
  const float* X    = (const float*)d_in[0];
  const float* W1   = (const float*)d_in[1];
  const float* b1   = (const float*)d_in[2];
  const float* ln_g = (const float*)d_in[3];
  const float* ln_b = (const float*)d_in[4];
  const float* W2   = (const float*)d_in[5];
  const float* b2   = (const float*)d_in[6];
  const float* Wl   = (const float*)d_in[7];
  const float* bl   = (const float*)d_in[8];
  const float* Wr   = (const float*)d_in[9];
  float* ws = (float*)d_ws;
  float* F      = ws + OFF_F;
  float* cnt    = ws + OFF_CNT;
  float* sums   = ws + OFF_SUMS;
  int*   nodeCnt= (int*)(ws + OFF_NCNT);
  float* logits = ws + OFF_LOGITS;
  int*   cols   = (int*)(ws + OFF_COLS);
  int*   ranks  = (int*)(ws + OFF_RANKS);
  float* fiSel  = ws + OFF_FISEL;
  int*   nodeList=(int*)(ws + OFF_NLIST);
  float* agg    = ws + OFF_AGG;
  float* hcBuf  = ws + OFF_HC;
  float* out    = (float*)d_out;

  // only sums (32 f) + nodeCnt (256 i) need zeroing now
  hipMemsetAsync(ws + OFF_SUMS, 0, (size_t)(SZ_SUMS+SZ_NCNT)*sizeof(float), stream);

  k_logits  <<<dim3(NN*CCC/MT), dim3(256), 0, stream>>>(X, W1, b1, ln_g, ln_b, W2, b2, logits);
  k_topk    <<<dim3(NN/256), dim3(256), 0, stream>>>(logits, cols, ranks, fiSel, nodeCnt, nodeList);
  k_accF    <<<dim3(4,16), dim3(256), 0, stream>>>(X, ranks, fiSel, nodeCnt, nodeList, F, cnt);
  k_graphagg<<<dim3(4,16), dim3(256), 0, stream>>>(F, cnt, agg);
  k_aggwl   <<<dim3((NCLS+MT-1)/MT,16), dim3(256), 0, stream>>>(agg, Wl, bl);
  k_hc2     <<<dim3((NN/MT),16), dim3(256), 0, stream>>>(X, Wr, ranks, fiSel, nodeCnt, nodeList, agg, hcBuf, sums);
  k_out     <<<dim3(NN*KTOP*HH/256), dim3(256), 0, stream>>>(hcBuf, cols, nodeCnt, sums, out);
}

// Round 6
// 208.376 us; speedup vs baseline: 1.3374x; 1.3374x over previous
//
#include <hip/hip_runtime.h>
#include <hip/hip_bf16.h>

#define NN 3072
#define CCC 16
#define HH 128
#define KTOP 4
#define NCLS 455   // C(15,3)
#define NUP 120    // 15 singles + 105 pairs
#define EPSF 1e-5f

// ---------------- ws layout (float offsets) ----------------
#define OFF_F       0
#define SZ_F        (16*NCLS*HH)            // 931840
#define OFF_CNT     (OFF_F + SZ_F)          // class counts (float), 7280
#define SZ_CNT      (16*NCLS)
#define OFF_SUMS    (OFF_CNT + SZ_CNT)      // sumHc[16], sumSq[16]
#define SZ_SUMS     32
#define OFF_NCNT    (OFF_SUMS + SZ_SUMS)    // int nodeCnt[16*16] (64B-padded per counter)
#define SZ_NCNT     256
#define ZERO_FLOATS (OFF_NCNT + SZ_NCNT)
#define OFF_LOGITS  ZERO_FLOATS
#define SZ_LOGITS   (NN*CCC)
#define OFF_COLS    (OFF_LOGITS + SZ_LOGITS)   // int, per (n,slot)
#define SZ_E        (NN*KTOP)
#define OFF_RANKS   (OFF_COLS + SZ_E)          // int
#define OFF_FISEL   (OFF_RANKS + SZ_E)         // float
#define OFF_NLIST   (OFF_FISEL + SZ_E)         // int, 16*NN
#define SZ_NLIST    (16*NN)
#define OFF_UP      (OFF_NLIST + SZ_NLIST)     // 16*120*128
#define SZ_UP       (16*NUP*HH)
#define OFF_AGG     (OFF_UP + SZ_UP)           // 16*455*128 (reused in-place for AggWl)
#define OFF_HC      (OFF_AGG + SZ_F)           // 12288*128
#define SZ_HC       (NN*KTOP*HH)

__device__ __forceinline__ int C2i(int x){ return x*(x-1)/2; }
__device__ __forceinline__ int C3i(int x){ return x*(x-1)*(x-2)/6; }

// rank -> triple bitmask over 15 relabeled columns
__device__ __forceinline__ unsigned decode_mask(int r){
  int c = 2; while (c < 14 && C3i(c+1) <= r) c++;
  int rem = r - C3i(c);
  int b = 1; while (b < c-1 && C2i(b+1) <= rem) b++;
  int a = rem - C2i(b);
  return (1u<<a) | (1u<<b) | (1u<<c);
}

// shared GEMM inner-step macro: k stepped by 2, activations as explicit
// float2 (b64 LDS reads), weights as float4 (b128, 2-way bank alias = free).
#define GEMM_INNER_KPAIR(xsArr, wchArr, accArr) \
  { \
    const float* x0 = &xsArr[tr*4+0][k0]; \
    const float* x1 = &xsArr[tr*4+1][k0]; \
    const float* x2 = &xsArr[tr*4+2][k0]; \
    const float* x3 = &xsArr[tr*4+3][k0]; \
    _Pragma("unroll 4") \
    for (int k = 0; k < KC; k += 2){ \
      float2 a0 = *(const float2*)&x0[k]; \
      float2 a1 = *(const float2*)&x1[k]; \
      float2 a2 = *(const float2*)&x2[k]; \
      float2 a3 = *(const float2*)&x3[k]; \
      _Pragma("unroll") \
      for (int kk = 0; kk < 2; ++kk){ \
        float4 wA = *(const float4*)&wchArr[k+kk][tc*4]; \
        float4 wB = *(const float4*)&wchArr[k+kk][64 + tc*4]; \
        float w[8] = {wA.x,wA.y,wA.z,wA.w,wB.x,wB.y,wB.z,wB.w}; \
        float b0 = kk ? a0.y : a0.x; \
        float b1 = kk ? a1.y : a1.x; \
        float b2_ = kk ? a2.y : a2.x; \
        float b3 = kk ? a3.y : a3.x; \
        _Pragma("unroll") \
        for (int j=0;j<8;++j){ \
          accArr[0][j] += b0*w[j]; accArr[1][j] += b1*w[j]; \
          accArr[2][j] += b2_*w[j]; accArr[3][j] += b3*w[j]; \
        } \
      } \
    } \
  }

// ================= stage A: z=relu(X@W1^T+b1); LN; logit=zn.W2+b2 =================
#define MT 64
#define KC 32
__global__ __launch_bounds__(256) void k_logits(const float* __restrict__ X,
    const float* __restrict__ W1, const float* __restrict__ b1,
    const float* __restrict__ ln_g, const float* __restrict__ ln_b,
    const float* __restrict__ W2, const float* __restrict__ b2,
    float* __restrict__ logits){
  __shared__ float xs[MT][132];
  __shared__ float wch[KC][128];
  int t = threadIdx.x;
  int tr = t >> 4;
  int tc = t & 15;
  int base = blockIdx.x * MT;

  for (int idx = t; idx < MT*32; idx += 256){
    int r = idx >> 5, c4 = (idx & 31) << 2;
    float4 v = *(const float4*)(X + (size_t)(base + r)*HH + c4);
    xs[r][c4] = v.x; xs[r][c4+1] = v.y; xs[r][c4+2] = v.z; xs[r][c4+3] = v.w;
  }

  float acc[4][8];
  #pragma unroll
  for (int i=0;i<4;++i)
    #pragma unroll
    for (int j=0;j<8;++j) acc[i][j]=0.f;

  for (int k0 = 0; k0 < HH; k0 += KC){
    __syncthreads();
    {
      int o = t & 127, half = t >> 7;
      #pragma unroll
      for (int q = 0; q < 2; ++q){
        int kk = half*16 + q*8;
        float4 a = *(const float4*)(W1 + o*HH + k0 + kk);
        float4 b = *(const float4*)(W1 + o*HH + k0 + kk + 4);
        wch[kk+0][o]=a.x; wch[kk+1][o]=a.y; wch[kk+2][o]=a.z; wch[kk+3][o]=a.w;
        wch[kk+4][o]=b.x; wch[kk+5][o]=b.y; wch[kk+6][o]=b.z; wch[kk+7][o]=b.w;
      }
    }
    __syncthreads();
    GEMM_INNER_KPAIR(xs, wch, acc)
  }

  float4 bA = *(const float4*)(b1 + tc*4),  bB = *(const float4*)(b1 + 64 + tc*4);
  float4 gA = *(const float4*)(ln_g + tc*4), gB = *(const float4*)(ln_g + 64 + tc*4);
  float4 lA = *(const float4*)(ln_b + tc*4), lB = *(const float4*)(ln_b + 64 + tc*4);
  float4 wA2 = *(const float4*)(W2 + tc*4),  wB2 = *(const float4*)(W2 + 64 + tc*4);
  float bv[8] = {bA.x,bA.y,bA.z,bA.w,bB.x,bB.y,bB.z,bB.w};
  float gv[8] = {gA.x,gA.y,gA.z,gA.w,gB.x,gB.y,gB.z,gB.w};
  float lv[8] = {lA.x,lA.y,lA.z,lA.w,lB.x,lB.y,lB.z,lB.w};
  float wv[8] = {wA2.x,wA2.y,wA2.z,wA2.w,wB2.x,wB2.y,wB2.z,wB2.w};
  float b2v = b2[0];
  #pragma unroll
  for (int i=0;i<4;++i){
    float s1=0.f, s2=0.f;
    #pragma unroll
    for (int j=0;j<8;++j){
      float z = acc[i][j] + bv[j]; z = z>0.f?z:0.f;
      acc[i][j] = z; s1 += z; s2 += z*z;
    }
    #pragma unroll
    for (int m=1;m<16;m<<=1){ s1 += __shfl_xor(s1,m); s2 += __shfl_xor(s2,m); }
    float mu = s1/(float)HH;
    float var = s2/(float)HH - mu*mu;
    float rs = 1.0f/sqrtf(var+EPSF);
    float s3 = 0.f;
    #pragma unroll
    for (int j=0;j<8;++j){
      float zn = (acc[i][j]-mu)*rs*gv[j] + lv[j];
      s3 += zn*wv[j];
    }
    #pragma unroll
    for (int m=1;m<16;m<<=1) s3 += __shfl_xor(s3,m);
    if (tc == 0) logits[base + tr*4 + i] = s3 + b2v;
  }
}

// ================= stage B: softmax fi, top-4, class ranks, node lists =================
__global__ __launch_bounds__(256) void k_topk(const float* __restrict__ logits,
    int* __restrict__ cols, int* __restrict__ ranks, float* __restrict__ fiSel,
    int* __restrict__ nodeCnt, int* __restrict__ nodeList){
  __shared__ int lcnt[CCC];
  __shared__ int lbase[CCC];
  int t = threadIdx.x;
  if (t < CCC) lcnt[t] = 0;
  __syncthreads();
  int n = blockIdx.x*256 + t;
  float l[CCC];
  #pragma unroll
  for (int c=0;c<CCC;++c) l[c] = logits[n*CCC+c];
  unsigned mask = 0;
  #pragma unroll
  for (int k=0;k<KTOP;++k){
    float best = -3e38f; int bi = 0;
    #pragma unroll
    for (int c=0;c<CCC;++c){
      bool taken = (mask>>c)&1u;
      if (!taken && l[c] > best){ best = l[c]; bi = c; }
    }
    mask |= 1u<<bi;
  }
  float m = -3e38f;
  #pragma unroll
  for (int c=0;c<CCC;++c) m = l[c]>m ? l[c] : m;
  float s = 0.f;
  #pragma unroll
  for (int c=0;c<CCC;++c) s += expf(l[c]-m);
  float inv = 1.0f/s;
  int mycis[KTOP], mypos[KTOP];
  unsigned m2 = mask;
  for (int j=0;j<KTOP;++j){
    int ci = __ffs(m2)-1; m2 &= m2-1u;
    unsigned rest = mask & ~(1u<<ci);
    int v[3]; unsigned r2 = rest;
    #pragma unroll
    for (int q=0;q<3;++q){ int col = __ffs(r2)-1; r2 &= r2-1u; v[q] = col - (col>ci ? 1:0); }
    int rank = C3i(v[2]) + C2i(v[1]) + v[0];
    int e4 = n*KTOP + j;
    cols[e4] = ci; ranks[e4] = rank;
    fiSel[e4] = expf(l[ci]-m)*inv;
    mycis[j] = ci;
    mypos[j] = atomicAdd(&lcnt[ci], 1);
  }
  __syncthreads();
  if (t < CCC) lbase[t] = atomicAdd(&nodeCnt[t*16], lcnt[t]);
  __syncthreads();
  #pragma unroll
  for (int j=0;j<KTOP;++j){
    int ci = mycis[j];
    nodeList[ci*NN + lbase[ci] + mypos[j]] = n*KTOP + j;
  }
}

// ================= stage C: class feature sums (global atomics, 6144 blocks) ==========
__global__ __launch_bounds__(256) void k_accF(const float* __restrict__ X,
    const int* __restrict__ cols, const int* __restrict__ ranks,
    const float* __restrict__ fiSel, float* __restrict__ F, float* __restrict__ cnt){
  int e = blockIdx.x*2 + (threadIdx.x>>7);
  int h = threadIdx.x & 127;
  int ci = cols[e], rank = ranks[e];
  float fi = fiSel[e];
  int n = e >> 2;
  float v = X[(n*CCC+ci)*HH + h] * fi;
  atomicAdd(&F[(ci*NCLS+rank)*HH + h], v);
  if (h==0) atomicAdd(&cnt[ci*NCLS+rank], 1.0f);
}

// ================= stage D1a: pairs P_xy = sum_z F[{x,y,z}] (13 direct summands) =================
__global__ __launch_bounds__(128) void k_pairs(const float* __restrict__ F, float* __restrict__ UP){
  int t = threadIdx.x;
  int p = blockIdx.x, ci = blockIdx.y;
  int pb = 1; while (pb < 14 && C2i(pb+1) <= p) pb++;
  int pa = p - C2i(pb);
  const float* Fc = F + (size_t)ci*NCLS*HH;
  float acc = 0.f;
  #pragma unroll
  for (int z = 0; z < 15; ++z){
    if (z == pa || z == pb) continue;
    int lo, mid, hi;
    if (z < pa){ lo = z;  mid = pa; hi = pb; }
    else if (z < pb){ lo = pa; mid = z;  hi = pb; }
    else { lo = pa; mid = pb; hi = z; }
    int rank = C3i(hi) + C2i(mid) + lo;
    acc += Fc[(size_t)rank*HH + t];
  }
  UP[((size_t)ci*NUP + 15 + p)*HH + t] = acc;
}

// ================= stage D1b: singles U_x = 0.5 * sum_{y!=x} P_xy =================
__global__ __launch_bounds__(128) void k_singles(float* __restrict__ UP){
  int t = threadIdx.x;
  int x = blockIdx.x, ci = blockIdx.y;
  const float* Pc = UP + ((size_t)ci*NUP + 15)*HH;
  float acc = 0.f;
  #pragma unroll
  for (int y = 0; y < 15; ++y){
    if (y == x) continue;
    int lo = x < y ? x : y, hi = x < y ? y : x;
    int pi = C2i(hi) + lo;
    acc += Pc[(size_t)pi*HH + t];
  }
  UP[((size_t)ci*NUP + x)*HH + t] = 0.5f*acc;
}

// ================= stage D2: per-class agg via inclusion-exclusion (+deg fused) =================
__global__ __launch_bounds__(128) void k_as(const float* __restrict__ F,
    const float* __restrict__ UP, const float* __restrict__ cnt, float* __restrict__ agg){
  __shared__ unsigned tm[NCLS];
  __shared__ float dred[2];
  int t = threadIdx.x;
  for (int i=t;i<NCLS;i+=128) tm[i] = decode_mask(i);
  __syncthreads();
  int r = blockIdx.x, ci = blockIdx.y;
  unsigned m = tm[r];
  float d = 0.f;
  const float* cc = cnt + ci*NCLS;
  for (int tp=t; tp<NCLS; tp+=128)
    if (m & tm[tp]) d += cc[tp];
  #pragma unroll
  for (int mm=1; mm<64; mm<<=1) d += __shfl_xor(d, mm);
  if ((t&63)==0) dred[t>>6] = d;
  __syncthreads();
  float invd = 1.0f / fmaxf(dred[0]+dred[1], 1.0f);
  int c = 2; while (c < 14 && C3i(c+1) <= r) c++;
  int rem = r - C3i(c);
  int b = 1; while (b < c-1 && C2i(b+1) <= rem) b++;
  int a = rem - C2i(b);
  const float* U = UP + ci*NUP*HH;
  int pab = 15 + C2i(b) + a;
  int pac = 15 + C2i(c) + a;
  int pbc = 15 + C2i(c) + b;
  float v = U[a*HH+t] + U[b*HH+t] + U[c*HH+t]
          - U[pab*HH+t] - U[pac*HH+t] - U[pbc*HH+t]
          + F[(ci*NCLS+r)*HH + t];
  agg[(ci*NCLS+r)*HH + t] = v * invd;
}

// ================= stage E1: AggWl = Agg @ Wl^T + bl (per class, in-place) =================
__global__ __launch_bounds__(256) void k_aggwl(float* __restrict__ agg,
    const float* __restrict__ Wl, const float* __restrict__ bl){
  __shared__ float xs[MT][132];
  __shared__ float wch[KC][128];
  int t = threadIdx.x;
  int tr = t >> 4, tc = t & 15;
  int ci = blockIdx.y;
  int base = blockIdx.x * MT;

  float* A = agg + (size_t)ci*NCLS*HH;
  for (int idx = t; idx < MT*32; idx += 256){
    int r = idx >> 5, c4 = (idx & 31) << 2;
    int rg = base + r; if (rg > NCLS-1) rg = NCLS-1;
    float4 v = *(const float4*)(A + (size_t)rg*HH + c4);
    xs[r][c4] = v.x; xs[r][c4+1] = v.y; xs[r][c4+2] = v.z; xs[r][c4+3] = v.w;
  }

  float acc[4][8];
  #pragma unroll
  for (int i=0;i<4;++i)
    #pragma unroll
    for (int j=0;j<8;++j) acc[i][j]=0.f;

  const float* W = Wl + (size_t)ci*HH*HH;
  for (int k0 = 0; k0 < HH; k0 += KC){
    __syncthreads();
    {
      int o = t & 127, half = t >> 7;
      #pragma unroll
      for (int q = 0; q < 2; ++q){
        int kk = half*16 + q*8;
        float4 a = *(const float4*)(W + o*HH + k0 + kk);
        float4 b = *(const float4*)(W + o*HH + k0 + kk + 4);
        wch[kk+0][o]=a.x; wch[kk+1][o]=a.y; wch[kk+2][o]=a.z; wch[kk+3][o]=a.w;
        wch[kk+4][o]=b.x; wch[kk+5][o]=b.y; wch[kk+6][o]=b.z; wch[kk+7][o]=b.w;
      }
    }
    __syncthreads();
    GEMM_INNER_KPAIR(xs, wch, acc)
  }
  float4 blA = *(const float4*)(bl + ci*HH + tc*4);
  float4 blB = *(const float4*)(bl + ci*HH + 64 + tc*4);
  #pragma unroll
  for (int i=0;i<4;++i){
    int row = base + tr*4 + i;
    if (row < NCLS){
      float4 oA = { acc[i][0]+blA.x, acc[i][1]+blA.y, acc[i][2]+blA.z, acc[i][3]+blA.w };
      float4 oB = { acc[i][4]+blB.x, acc[i][5]+blB.y, acc[i][6]+blB.z, acc[i][7]+blB.w };
      *(float4*)(A + (size_t)row*HH + tc*4) = oA;
      *(float4*)(A + (size_t)row*HH + 64 + tc*4) = oB;
    }
  }
}

// ================= stage E2: hc = relu(AggWl[class] + fi*X @ Wr^T) per node =================
__global__ __launch_bounds__(256) void k_hc2(const float* __restrict__ X,
    const float* __restrict__ Wr,
    const int* __restrict__ ranks, const float* __restrict__ fiSel,
    const int* __restrict__ nodeCnt, const int* __restrict__ nodeList,
    const float* __restrict__ aggwl, float* __restrict__ hcBuf, float* __restrict__ sums){
  int ci = blockIdx.y;
  int cntc = nodeCnt[ci*16];
  int base = blockIdx.x * MT;
  if (base >= cntc) return;
  __shared__ float xs[MT][132];
  __shared__ float wch[KC][128];
  __shared__ int   es[MT];
  __shared__ float fis[MT];
  __shared__ int   rks[MT];
  __shared__ float rb[8];
  int t = threadIdx.x;
  int tr = t >> 4, tc = t & 15;
  if (t < MT){
    int p = base + t;
    if (p < cntc){
      int e = nodeList[ci*NN + p];
      es[t] = e; fis[t] = fiSel[e]; rks[t] = ranks[e];
    } else { es[t] = -1; fis[t] = 0.f; rks[t] = 0; }
  }
  __syncthreads();
  for (int idx = t; idx < MT*32; idx += 256){
    int r = idx >> 5, c4 = (idx & 31) << 2;
    int e = es[r];
    if (e >= 0){
      int n = e >> 2;
      float fi = fis[r];
      float4 v = *(const float4*)(X + (size_t)(n*CCC+ci)*HH + c4);
      xs[r][c4] = v.x*fi; xs[r][c4+1] = v.y*fi; xs[r][c4+2] = v.z*fi; xs[r][c4+3] = v.w*fi;
    } else {
      xs[r][c4]=0.f; xs[r][c4+1]=0.f; xs[r][c4+2]=0.f; xs[r][c4+3]=0.f;
    }
  }

  float acc[4][8];
  #pragma unroll
  for (int i=0;i<4;++i)
    #pragma unroll
    for (int j=0;j<8;++j) acc[i][j]=0.f;

  const float* W = Wr + (size_t)ci*HH*HH;
  for (int k0 = 0; k0 < HH; k0 += KC){
    __syncthreads();
    {
      int o = t & 127, half = t >> 7;
      #pragma unroll
      for (int q = 0; q < 2; ++q){
        int kk = half*16 + q*8;
        float4 a = *(const float4*)(W + o*HH + k0 + kk);
        float4 b = *(const float4*)(W + o*HH + k0 + kk + 4);
        wch[kk+0][o]=a.x; wch[kk+1][o]=a.y; wch[kk+2][o]=a.z; wch[kk+3][o]=a.w;
        wch[kk+4][o]=b.x; wch[kk+5][o]=b.y; wch[kk+6][o]=b.z; wch[kk+7][o]=b.w;
      }
    }
    __syncthreads();
    GEMM_INNER_KPAIR(xs, wch, acc)
  }

  float s1 = 0.f, s2 = 0.f;
  #pragma unroll
  for (int i=0;i<4;++i){
    int r = tr*4 + i;
    int e = es[r];
    if (e >= 0){
      int rank = rks[r];
      const float* G = aggwl + (size_t)(ci*NCLS + rank)*HH;
      float4 gA = *(const float4*)(G + tc*4);
      float4 gB = *(const float4*)(G + 64 + tc*4);
      float g[8] = {gA.x,gA.y,gA.z,gA.w,gB.x,gB.y,gB.z,gB.w};
      float hc[8];
      #pragma unroll
      for (int j=0;j<8;++j){
        float v = acc[i][j] + g[j];
        v = v>0.f ? v : 0.f;
        hc[j] = v; s1 += v; s2 += v*v;
      }
      float4 oA = {hc[0],hc[1],hc[2],hc[3]};
      float4 oB = {hc[4],hc[5],hc[6],hc[7]};
      *(float4*)(hcBuf + (size_t)e*HH + tc*4) = oA;
      *(float4*)(hcBuf + (size_t)e*HH + 64 + tc*4) = oB;
    }
  }
  #pragma unroll
  for (int m=1;m<64;m<<=1){ s1 += __shfl_xor(s1,m); s2 += __shfl_xor(s2,m); }
  int wid = t >> 6;
  if ((t&63)==0){ rb[wid] = s1; rb[4+wid] = s2; }
  __syncthreads();
  if (t==0){
    atomicAdd(&sums[ci],    rb[0]+rb[1]+rb[2]+rb[3]);
    atomicAdd(&sums[16+ci], rb[4]+rb[5]+rb[6]+rb[7]);
  }
}

// ================= stage F: masked mean/var normalize, write output =================
__global__ __launch_bounds__(256) void k_out(const float* __restrict__ hcBuf,
    const int* __restrict__ cols, const int* __restrict__ nodeCnt,
    const float* __restrict__ sums, float* __restrict__ out){
  int idx = blockIdx.x*256 + threadIdx.x;
  int e = idx >> 7;
  int ci = cols[e];
  float cntf = (float)nodeCnt[ci*16];
  float nel = fmaxf(cntf * (float)HH, 1.0f);
  float mu = sums[ci]/nel;
  float var = sums[16+ci]/nel - mu*mu;
  out[idx] = (hcBuf[idx]-mu)/sqrtf(var+EPSF);
}

extern "C" void kernel_launch(void* const* d_in, const int* in_sizes, int n_in,
                              void* d_out, int out_size, void* d_ws, size_t ws_size,
                              hipStream_t stream){
  const float* X    = (const float*)d_in[0];
  const float* W1   = (const float*)d_in[1];
  const float* b1   = (const float*)d_in[2];
  const float* ln_g = (const float*)d_in[3];
  const float* ln_b = (const float*)d_in[4];
  const float* W2   = (const float*)d_in[5];
  const float* b2   = (const float*)d_in[6];
  const float* Wl   = (const float*)d_in[7];
  const float* bl   = (const float*)d_in[8];
  const float* Wr   = (const float*)d_in[9];
  float* ws = (float*)d_ws;
  float* F      = ws + OFF_F;
  float* cnt    = ws + OFF_CNT;
  float* sums   = ws + OFF_SUMS;
  int*   nodeCnt= (int*)(ws + OFF_NCNT);
  float* logits = ws + OFF_LOGITS;
  int*   cols   = (int*)(ws + OFF_COLS);
  int*   ranks  = (int*)(ws + OFF_RANKS);
  float* fiSel  = ws + OFF_FISEL;
  int*   nodeList=(int*)(ws + OFF_NLIST);
  float* UP     = ws + OFF_UP;
  float* agg    = ws + OFF_AGG;
  float* hcBuf  = ws + OFF_HC;
  float* out    = (float*)d_out;

  hipMemsetAsync(ws, 0, (size_t)ZERO_FLOATS*sizeof(float), stream);

  k_logits <<<dim3(NN*CCC/MT), dim3(256), 0, stream>>>(X, W1, b1, ln_g, ln_b, W2, b2, logits);
  k_topk   <<<dim3(NN/256), dim3(256), 0, stream>>>(logits, cols, ranks, fiSel, nodeCnt, nodeList);
  k_accF   <<<dim3(NN*KTOP/2), dim3(256), 0, stream>>>(X, cols, ranks, fiSel, F, cnt);
  k_pairs  <<<dim3(105,16), dim3(128), 0, stream>>>(F, UP);
  k_singles<<<dim3(15,16), dim3(128), 0, stream>>>(UP);
  k_as     <<<dim3(NCLS,16), dim3(128), 0, stream>>>(F, UP, cnt, agg);
  k_aggwl  <<<dim3((NCLS+MT-1)/MT,16), dim3(256), 0, stream>>>(agg, Wl, bl);
  k_hc2    <<<dim3((NN/MT),16), dim3(256), 0, stream>>>(X, Wr, ranks, fiSel, nodeCnt, nodeList, agg, hcBuf, sums);
  k_out    <<<dim3(NN*KTOP*HH/256), dim3(256), 0, stream>>>(hcBuf, cols, nodeCnt, sums, out);
}

// Round 7
// 194.922 us; speedup vs baseline: 1.4297x; 1.0690x over previous
//
#include <hip/hip_runtime.h>
#include <hip/hip_bf16.h>

#define NN 3072
#define CCC 16
#define HH 128
#define KTOP 4
#define NCLS 455   // C(15,3)
#define NUP 120    // 15 singles + 105 pairs
#define EPSF 1e-5f

// ---------------- ws layout (float offsets) ----------------
#define OFF_F       0
#define SZ_F        (16*NCLS*HH)            // 931840
#define OFF_CNT     (OFF_F + SZ_F)          // class counts (float), 7280
#define SZ_CNT      (16*NCLS)
#define OFF_SUMS    (OFF_CNT + SZ_CNT)      // sumHc[16], sumSq[16]
#define SZ_SUMS     32
#define OFF_NCNT    (OFF_SUMS + SZ_SUMS)    // int nodeCnt[16*16] (64B-padded per counter)
#define SZ_NCNT     256
#define ZERO_FLOATS (OFF_NCNT + SZ_NCNT)
#define OFF_LOGITS  ZERO_FLOATS
#define SZ_LOGITS   (NN*CCC)
#define OFF_COLS    (OFF_LOGITS + SZ_LOGITS)   // int, per (n,slot)
#define SZ_E        (NN*KTOP)
#define OFF_RANKS   (OFF_COLS + SZ_E)          // int
#define OFF_FISEL   (OFF_RANKS + SZ_E)         // float
#define OFF_NLIST   (OFF_FISEL + SZ_E)         // int, 16*NN
#define SZ_NLIST    (16*NN)
#define OFF_UP      (OFF_NLIST + SZ_NLIST)     // 16*120*128
#define SZ_UP       (16*NUP*HH)
#define OFF_AGG     (OFF_UP + SZ_UP)           // 16*455*128 (reused in-place for AggWl)
#define OFF_HC      (OFF_AGG + SZ_F)           // 12288*128
#define SZ_HC       (NN*KTOP*HH)
#define OFF_HALF    (OFF_HC + SZ_HC)           // f16 weight copies (as halves)
// half offsets within the f16 region:
#define HOFF_W1H    0
#define HOFF_W1L    16384
#define HOFF_WLH    32768
#define HOFF_WRH    (32768 + 262144)
#define CVT_TOTAL   (16384 + 262144 + 262144)

typedef _Float16 h8 __attribute__((ext_vector_type(8)));
typedef float    f4 __attribute__((ext_vector_type(4)));

__device__ __forceinline__ int C2i(int x){ return x*(x-1)/2; }
__device__ __forceinline__ int C3i(int x){ return x*(x-1)*(x-2)/6; }

__device__ __forceinline__ unsigned decode_mask(int r){
  int c = 2; while (c < 14 && C3i(c+1) <= r) c++;
  int rem = r - C3i(c);
  int b = 1; while (b < c-1 && C2i(b+1) <= rem) b++;
  int a = rem - C2i(b);
  return (1u<<a) | (1u<<b) | (1u<<c);
}

#define MT 64

// ================= stage 0: weight conversion to f16 (hi/lo for W1) =================
__global__ __launch_bounds__(256) void k_cvt(const float* __restrict__ W1,
    const float* __restrict__ Wl, const float* __restrict__ Wr,
    _Float16* __restrict__ hbase){
  int i = blockIdx.x*256 + threadIdx.x;
  if (i < 16384){
    float x = W1[i];
    _Float16 h = (_Float16)x;
    hbase[HOFF_W1H + i] = h;
    hbase[HOFF_W1L + i] = (_Float16)(x - (float)h);
  }
  int j = i - 16384;
  if (j >= 0 && j < 262144) hbase[HOFF_WLH + j] = (_Float16)Wl[j];
  int k2 = i - (16384 + 262144);
  if (k2 >= 0 && k2 < 262144) hbase[HOFF_WRH + k2] = (_Float16)Wr[k2];
}

// ================= stage A: z=relu(X@W1^T+b1); LN; logit=zn.W2+b2 =================
// MFMA 16x16x32 f16 with 2-way split (hi+lo) for f32-grade precision.
// Block: 256 thr = 4 waves; tile 64 rows x 128 o; wave w owns rows 16w..16w+15.
// No LDS, no barriers: A-frags in registers, B-frags stream from f16 weights.
__global__ __launch_bounds__(256) void k_logits(const float* __restrict__ X,
    const _Float16* __restrict__ W1h, const _Float16* __restrict__ W1l,
    const float* __restrict__ b1, const float* __restrict__ ln_g,
    const float* __restrict__ ln_b, const float* __restrict__ W2,
    const float* __restrict__ b2, float* __restrict__ logits){
  int t = threadIdx.x;
  int w = t >> 6;
  int lane = t & 63;
  int l15 = lane & 15, quad = lane >> 4;
  int base = blockIdx.x * MT;
  int mA = base + 16*w + l15;

  // A fragments: A[m=l15][k=quad*8+j] per 32-k chunk c
  const float* xrow = X + (size_t)mA*HH;
  h8 ah[4], al[4];
  #pragma unroll
  for (int c=0;c<4;++c){
    float4 u = *(const float4*)(xrow + c*32 + quad*8);
    float4 v = *(const float4*)(xrow + c*32 + quad*8 + 4);
    float xv[8] = {u.x,u.y,u.z,u.w,v.x,v.y,v.z,v.w};
    #pragma unroll
    for (int j=0;j<8;++j){
      _Float16 hi = (_Float16)xv[j];
      ah[c][j] = hi;
      al[c][j] = (_Float16)(xv[j] - (float)hi);
    }
  }

  f4 acc[8];
  #pragma unroll
  for (int nt=0;nt<8;++nt) acc[nt] = (f4){0.f,0.f,0.f,0.f};

  #pragma unroll
  for (int c=0;c<4;++c){
    #pragma unroll
    for (int nt=0;nt<8;++nt){
      int o = nt*16 + l15;
      const _Float16* ph = W1h + (size_t)o*HH + c*32 + quad*8;
      const _Float16* pl = W1l + (size_t)o*HH + c*32 + quad*8;
      h8 bh = *(const h8*)ph;
      h8 bl_ = *(const h8*)pl;
      acc[nt] = __builtin_amdgcn_mfma_f32_16x16x32_f16(ah[c], bh,  acc[nt], 0,0,0);
      acc[nt] = __builtin_amdgcn_mfma_f32_16x16x32_f16(al[c], bh,  acc[nt], 0,0,0);
      acc[nt] = __builtin_amdgcn_mfma_f32_16x16x32_f16(ah[c], bl_, acc[nt], 0,0,0);
      acc[nt] = __builtin_amdgcn_mfma_f32_16x16x32_f16(al[c], bl_, acc[nt], 0,0,0);
    }
  }

  // epilogue: D[m=quad*4+r][o=nt*16+l15]; relu + LN + dot(W2) per row
  float bv[8], gv[8], lv[8], wv[8];
  #pragma unroll
  for (int nt=0;nt<8;++nt){
    int o = nt*16 + l15;
    bv[nt]=b1[o]; gv[nt]=ln_g[o]; lv[nt]=ln_b[o]; wv[nt]=W2[o];
  }
  float b2v = b2[0];
  #pragma unroll
  for (int r=0;r<4;++r){
    float z[8];
    float s1=0.f, s2=0.f;
    #pragma unroll
    for (int nt=0;nt<8;++nt){
      float zz = acc[nt][r] + bv[nt];
      zz = zz>0.f ? zz : 0.f;
      z[nt] = zz; s1 += zz; s2 += zz*zz;
    }
    #pragma unroll
    for (int m=1;m<16;m<<=1){ s1 += __shfl_xor(s1,m); s2 += __shfl_xor(s2,m); }
    float mu = s1/(float)HH;
    float var = s2/(float)HH - mu*mu;
    float rs = 1.0f/sqrtf(var+EPSF);
    float s3 = 0.f;
    #pragma unroll
    for (int nt=0;nt<8;++nt){
      float zn = (z[nt]-mu)*rs*gv[nt] + lv[nt];
      s3 += zn*wv[nt];
    }
    #pragma unroll
    for (int m=1;m<16;m<<=1) s3 += __shfl_xor(s3,m);
    if (l15 == 0) logits[base + 16*w + quad*4 + r] = s3 + b2v;
  }
}

// ================= stage B: softmax fi, top-4, class ranks, node lists =================
__global__ __launch_bounds__(256) void k_topk(const float* __restrict__ logits,
    int* __restrict__ cols, int* __restrict__ ranks, float* __restrict__ fiSel,
    int* __restrict__ nodeCnt, int* __restrict__ nodeList){
  __shared__ int lcnt[CCC];
  __shared__ int lbase[CCC];
  int t = threadIdx.x;
  if (t < CCC) lcnt[t] = 0;
  __syncthreads();
  int n = blockIdx.x*256 + t;
  float l[CCC];
  #pragma unroll
  for (int c=0;c<CCC;++c) l[c] = logits[n*CCC+c];
  unsigned mask = 0;
  #pragma unroll
  for (int k=0;k<KTOP;++k){
    float best = -3e38f; int bi = 0;
    #pragma unroll
    for (int c=0;c<CCC;++c){
      bool taken = (mask>>c)&1u;
      if (!taken && l[c] > best){ best = l[c]; bi = c; }
    }
    mask |= 1u<<bi;
  }
  float m = -3e38f;
  #pragma unroll
  for (int c=0;c<CCC;++c) m = l[c]>m ? l[c] : m;
  float s = 0.f;
  #pragma unroll
  for (int c=0;c<CCC;++c) s += expf(l[c]-m);
  float inv = 1.0f/s;
  int mycis[KTOP], mypos[KTOP];
  unsigned m2 = mask;
  for (int j=0;j<KTOP;++j){
    int ci = __ffs(m2)-1; m2 &= m2-1u;
    unsigned rest = mask & ~(1u<<ci);
    int v[3]; unsigned r2 = rest;
    #pragma unroll
    for (int q=0;q<3;++q){ int col = __ffs(r2)-1; r2 &= r2-1u; v[q] = col - (col>ci ? 1:0); }
    int rank = C3i(v[2]) + C2i(v[1]) + v[0];
    int e4 = n*KTOP + j;
    cols[e4] = ci; ranks[e4] = rank;
    fiSel[e4] = expf(l[ci]-m)*inv;
    mycis[j] = ci;
    mypos[j] = atomicAdd(&lcnt[ci], 1);
  }
  __syncthreads();
  if (t < CCC) lbase[t] = atomicAdd(&nodeCnt[t*16], lcnt[t]);
  __syncthreads();
  #pragma unroll
  for (int j=0;j<KTOP;++j){
    int ci = mycis[j];
    nodeList[ci*NN + lbase[ci] + mypos[j]] = n*KTOP + j;
  }
}

// ================= stage C: class feature sums (global atomics, 6144 blocks) ==========
__global__ __launch_bounds__(256) void k_accF(const float* __restrict__ X,
    const int* __restrict__ cols, const int* __restrict__ ranks,
    const float* __restrict__ fiSel, float* __restrict__ F, float* __restrict__ cnt){
  int e = blockIdx.x*2 + (threadIdx.x>>7);
  int h = threadIdx.x & 127;
  int ci = cols[e], rank = ranks[e];
  float fi = fiSel[e];
  int n = e >> 2;
  float v = X[(n*CCC+ci)*HH + h] * fi;
  atomicAdd(&F[(ci*NCLS+rank)*HH + h], v);
  if (h==0) atomicAdd(&cnt[ci*NCLS+rank], 1.0f);
}

// ================= stage D1a: pairs P_xy = sum_z F[{x,y,z}] =================
__global__ __launch_bounds__(128) void k_pairs(const float* __restrict__ F, float* __restrict__ UP){
  int t = threadIdx.x;
  int p = blockIdx.x, ci = blockIdx.y;
  int pb = 1; while (pb < 14 && C2i(pb+1) <= p) pb++;
  int pa = p - C2i(pb);
  const float* Fc = F + (size_t)ci*NCLS*HH;
  float acc = 0.f;
  #pragma unroll
  for (int z = 0; z < 15; ++z){
    if (z == pa || z == pb) continue;
    int lo, mid, hi;
    if (z < pa){ lo = z;  mid = pa; hi = pb; }
    else if (z < pb){ lo = pa; mid = z;  hi = pb; }
    else { lo = pa; mid = pb; hi = z; }
    int rank = C3i(hi) + C2i(mid) + lo;
    acc += Fc[(size_t)rank*HH + t];
  }
  UP[((size_t)ci*NUP + 15 + p)*HH + t] = acc;
}

// ================= stage D1b: singles U_x = 0.5 * sum_{y!=x} P_xy =================
__global__ __launch_bounds__(128) void k_singles(float* __restrict__ UP){
  int t = threadIdx.x;
  int x = blockIdx.x, ci = blockIdx.y;
  const float* Pc = UP + ((size_t)ci*NUP + 15)*HH;
  float acc = 0.f;
  #pragma unroll
  for (int y = 0; y < 15; ++y){
    if (y == x) continue;
    int lo = x < y ? x : y, hi = x < y ? y : x;
    int pi = C2i(hi) + lo;
    acc += Pc[(size_t)pi*HH + t];
  }
  UP[((size_t)ci*NUP + x)*HH + t] = 0.5f*acc;
}

// ================= stage D2: per-class agg via inclusion-exclusion (+deg fused) =================
__global__ __launch_bounds__(128) void k_as(const float* __restrict__ F,
    const float* __restrict__ UP, const float* __restrict__ cnt, float* __restrict__ agg){
  __shared__ unsigned tm[NCLS];
  __shared__ float dred[2];
  int t = threadIdx.x;
  for (int i=t;i<NCLS;i+=128) tm[i] = decode_mask(i);
  __syncthreads();
  int r = blockIdx.x, ci = blockIdx.y;
  unsigned m = tm[r];
  float d = 0.f;
  const float* cc = cnt + ci*NCLS;
  for (int tp=t; tp<NCLS; tp+=128)
    if (m & tm[tp]) d += cc[tp];
  #pragma unroll
  for (int mm=1; mm<64; mm<<=1) d += __shfl_xor(d, mm);
  if ((t&63)==0) dred[t>>6] = d;
  __syncthreads();
  float invd = 1.0f / fmaxf(dred[0]+dred[1], 1.0f);
  int c = 2; while (c < 14 && C3i(c+1) <= r) c++;
  int rem = r - C3i(c);
  int b = 1; while (b < c-1 && C2i(b+1) <= rem) b++;
  int a = rem - C2i(b);
  const float* U = UP + ci*NUP*HH;
  int pab = 15 + C2i(b) + a;
  int pac = 15 + C2i(c) + a;
  int pbc = 15 + C2i(c) + b;
  float v = U[a*HH+t] + U[b*HH+t] + U[c*HH+t]
          - U[pab*HH+t] - U[pac*HH+t] - U[pbc*HH+t]
          + F[(ci*NCLS+r)*HH + t];
  agg[(ci*NCLS+r)*HH + t] = v * invd;
}

// ================= stage E1: AggWl = Agg @ Wl^T + bl (per class, in-place, f16 MFMA) ====
__global__ __launch_bounds__(256) void k_aggwl(float* __restrict__ agg,
    const _Float16* __restrict__ Wlh, const float* __restrict__ bl){
  int t = threadIdx.x;
  int w = t >> 6;
  int lane = t & 63;
  int l15 = lane & 15, quad = lane >> 4;
  int ci = blockIdx.y;
  int base = blockIdx.x * MT;
  int rowA = base + 16*w + l15; if (rowA > NCLS-1) rowA = NCLS-1;

  const float* arow = agg + ((size_t)ci*NCLS + rowA)*HH;
  h8 af[4];
  #pragma unroll
  for (int c=0;c<4;++c){
    float4 u = *(const float4*)(arow + c*32 + quad*8);
    float4 v = *(const float4*)(arow + c*32 + quad*8 + 4);
    float xv[8] = {u.x,u.y,u.z,u.w,v.x,v.y,v.z,v.w};
    #pragma unroll
    for (int j=0;j<8;++j) af[c][j] = (_Float16)xv[j];
  }

  f4 acc[8];
  #pragma unroll
  for (int nt=0;nt<8;++nt) acc[nt] = (f4){0.f,0.f,0.f,0.f};

  const _Float16* Wc = Wlh + (size_t)ci*HH*HH;
  #pragma unroll
  for (int c=0;c<4;++c){
    #pragma unroll
    for (int nt=0;nt<8;++nt){
      int o = nt*16 + l15;
      h8 bh = *(const h8*)(Wc + (size_t)o*HH + c*32 + quad*8);
      acc[nt] = __builtin_amdgcn_mfma_f32_16x16x32_f16(af[c], bh, acc[nt], 0,0,0);
    }
  }
  // epilogue: wave w writes rows base+16w+quad*4+r (same 16-row range it read)
  #pragma unroll
  for (int r=0;r<4;++r){
    int row2 = base + 16*w + quad*4 + r;
    if (row2 < NCLS){
      float* drow = agg + ((size_t)ci*NCLS + row2)*HH;
      #pragma unroll
      for (int nt=0;nt<8;++nt){
        int o = nt*16 + l15;
        drow[o] = acc[nt][r] + bl[ci*HH + o];
      }
    }
  }
}

// ================= stage E2: hc = relu(AggWl[class] + fi*X @ Wr^T) (f16 MFMA) =========
__global__ __launch_bounds__(256) void k_hc2(const float* __restrict__ X,
    const _Float16* __restrict__ Wrh,
    const int* __restrict__ ranks, const float* __restrict__ fiSel,
    const int* __restrict__ nodeCnt, const int* __restrict__ nodeList,
    const float* __restrict__ aggwl, float* __restrict__ hcBuf, float* __restrict__ sums){
  int ci = blockIdx.y;
  int cntc = nodeCnt[ci*16];
  int base = blockIdx.x * MT;
  if (base >= cntc) return;
  __shared__ float rb[8];
  int t = threadIdx.x;
  int w = t >> 6;
  int lane = t & 63;
  int l15 = lane & 15, quad = lane >> 4;

  int pA = base + 16*w + l15;
  float fi = 0.f; int nA = 0;
  if (pA < cntc){
    int e = nodeList[ci*NN + pA];
    fi = fiSel[e]; nA = e >> 2;
  }
  const float* xrow = X + ((size_t)nA*CCC + ci)*HH;
  h8 af[4];
  #pragma unroll
  for (int c=0;c<4;++c){
    float4 u = *(const float4*)(xrow + c*32 + quad*8);
    float4 v = *(const float4*)(xrow + c*32 + quad*8 + 4);
    float xv[8] = {u.x,u.y,u.z,u.w,v.x,v.y,v.z,v.w};
    #pragma unroll
    for (int j=0;j<8;++j) af[c][j] = (_Float16)(xv[j]*fi);
  }

  f4 acc[8];
  #pragma unroll
  for (int nt=0;nt<8;++nt) acc[nt] = (f4){0.f,0.f,0.f,0.f};

  const _Float16* Wc = Wrh + (size_t)ci*HH*HH;
  #pragma unroll
  for (int c=0;c<4;++c){
    #pragma unroll
    for (int nt=0;nt<8;++nt){
      int o = nt*16 + l15;
      h8 bh = *(const h8*)(Wc + (size_t)o*HH + c*32 + quad*8);
      acc[nt] = __builtin_amdgcn_mfma_f32_16x16x32_f16(af[c], bh, acc[nt], 0,0,0);
    }
  }

  // epilogue: D rows = base+16w+quad*4+r; gather AggWl[rank], relu, store, sums
  float s1 = 0.f, s2 = 0.f;
  #pragma unroll
  for (int r=0;r<4;++r){
    int pD = base + 16*w + quad*4 + r;
    int e2 = -1, rk2 = 0;
    if (pD < cntc){ e2 = nodeList[ci*NN + pD]; rk2 = ranks[e2]; }
    if (e2 >= 0){
      const float* G = aggwl + ((size_t)ci*NCLS + rk2)*HH;
      float* drow = hcBuf + (size_t)e2*HH;
      #pragma unroll
      for (int nt=0;nt<8;++nt){
        int o = nt*16 + l15;
        float vv = acc[nt][r] + G[o];
        vv = vv>0.f ? vv : 0.f;
        drow[o] = vv;
        s1 += vv; s2 += vv*vv;
      }
    }
  }
  #pragma unroll
  for (int m=1;m<64;m<<=1){ s1 += __shfl_xor(s1,m); s2 += __shfl_xor(s2,m); }
  if (lane == 0){ rb[w] = s1; rb[4+w] = s2; }
  __syncthreads();
  if (t==0){
    atomicAdd(&sums[ci],    rb[0]+rb[1]+rb[2]+rb[3]);
    atomicAdd(&sums[16+ci], rb[4]+rb[5]+rb[6]+rb[7]);
  }
}

// ================= stage F: masked mean/var normalize, write output =================
__global__ __launch_bounds__(256) void k_out(const float* __restrict__ hcBuf,
    const int* __restrict__ cols, const int* __restrict__ nodeCnt,
    const float* __restrict__ sums, float* __restrict__ out){
  int idx = blockIdx.x*256 + threadIdx.x;
  int e = idx >> 7;
  int ci = cols[e];
  float cntf = (float)nodeCnt[ci*16];
  float nel = fmaxf(cntf * (float)HH, 1.0f);
  float mu = sums[ci]/nel;
  float var = sums[16+ci]/nel - mu*mu;
  out[idx] = (hcBuf[idx]-mu)/sqrtf(var+EPSF);
}

extern "C" void kernel_launch(void* const* d_in, const int* in_sizes, int n_in,
                              void* d_out, int out_size, void* d_ws, size_t ws_size,
                              hipStream_t stream){
  const float* X    = (const float*)d_in[0];
  const float* W1   = (const float*)d_in[1];
  const float* b1   = (const float*)d_in[2];
  const float* ln_g = (const float*)d_in[3];
  const float* ln_b = (const float*)d_in[4];
  const float* W2   = (const float*)d_in[5];
  const float* b2   = (const float*)d_in[6];
  const float* Wl   = (const float*)d_in[7];
  const float* bl   = (const float*)d_in[8];
  const float* Wr   = (const float*)d_in[9];
  float* ws = (float*)d_ws;
  float* F      = ws + OFF_F;
  float* cnt    = ws + OFF_CNT;
  float* sums   = ws + OFF_SUMS;
  int*   nodeCnt= (int*)(ws + OFF_NCNT);
  float* logits = ws + OFF_LOGITS;
  int*   cols   = (int*)(ws + OFF_COLS);
  int*   ranks  = (int*)(ws + OFF_RANKS);
  float* fiSel  = ws + OFF_FISEL;
  int*   nodeList=(int*)(ws + OFF_NLIST);
  float* UP     = ws + OFF_UP;
  float* agg    = ws + OFF_AGG;
  float* hcBuf  = ws + OFF_HC;
  _Float16* hbase = (_Float16*)(ws + OFF_HALF);
  float* out    = (float*)d_out;

  hipMemsetAsync(ws, 0, (size_t)ZERO_FLOATS*sizeof(float), stream);

  k_cvt    <<<dim3((CVT_TOTAL+255)/256), dim3(256), 0, stream>>>(W1, Wl, Wr, hbase);
  k_logits <<<dim3(NN*CCC/MT), dim3(256), 0, stream>>>(X, hbase+HOFF_W1H, hbase+HOFF_W1L,
                                                       b1, ln_g, ln_b, W2, b2, logits);
  k_topk   <<<dim3(NN/256), dim3(256), 0, stream>>>(logits, cols, ranks, fiSel, nodeCnt, nodeList);
  k_accF   <<<dim3(NN*KTOP/2), dim3(256), 0, stream>>>(X, cols, ranks, fiSel, F, cnt);
  k_pairs  <<<dim3(105,16), dim3(128), 0, stream>>>(F, UP);
  k_singles<<<dim3(15,16), dim3(128), 0, stream>>>(UP);
  k_as     <<<dim3(NCLS,16), dim3(128), 0, stream>>>(F, UP, cnt, agg);
  k_aggwl  <<<dim3((NCLS+MT-1)/MT,16), dim3(256), 0, stream>>>(agg, hbase+HOFF_WLH, bl);
  k_hc2    <<<dim3((NN/MT),16), dim3(256), 0, stream>>>(X, hbase+HOFF_WRH, ranks, fiSel,
                                                        nodeCnt, nodeList, agg, hcBuf, sums);
  k_out    <<<dim3(NN*KTOP*HH/256), dim3(256), 0, stream>>>(hcBuf, cols, nodeCnt, sums, out);
}

// Round 8
// 192.791 us; speedup vs baseline: 1.4455x; 1.0111x over previous
//
#include <hip/hip_runtime.h>
#include <hip/hip_bf16.h>

#define NN 3072
#define CCC 16
#define HH 128
#define KTOP 4
#define NCLS 455   // C(15,3)
#define NUP 120
#define EPSF 1e-5f

// ---------------- ws layout (float offsets) ----------------
#define OFF_F       0
#define SZ_F        (16*NCLS*HH)            // 931840
#define OFF_CNT     (OFF_F + SZ_F)
#define SZ_CNT      (16*NCLS)
#define OFF_SUMS    (OFF_CNT + SZ_CNT)
#define SZ_SUMS     32
#define OFF_NCNT    (OFF_SUMS + SZ_SUMS)    // int nodeCnt[16*16] (64B-padded)
#define SZ_NCNT     256
#define ZERO_FLOATS (OFF_NCNT + SZ_NCNT)    // 939408 floats zeroed by k_cvt
#define OFF_LOGITS  ZERO_FLOATS
#define SZ_LOGITS   (NN*CCC)
#define OFF_COLS    (OFF_LOGITS + SZ_LOGITS)
#define SZ_E        (NN*KTOP)
#define OFF_RANKS   (OFF_COLS + SZ_E)
#define OFF_FISEL   (OFF_RANKS + SZ_E)
#define OFF_NLIST   (OFF_FISEL + SZ_E)
#define SZ_NLIST    (16*NN)
#define OFF_UP      (OFF_NLIST + SZ_NLIST)     // unused (layout stability)
#define SZ_UP       (16*NUP*HH)
#define OFF_AGG     (OFF_UP + SZ_UP)
#define OFF_HC      (OFF_AGG + SZ_F)
#define SZ_HC       (NN*KTOP*HH)
#define OFF_HALF    (OFF_HC + SZ_HC)
#define HOFF_W1H    0
#define HOFF_W1L    16384
#define HOFF_WLH    32768
#define HOFF_WRH    (32768 + 262144)
#define CVT_TOTAL   (16384 + 262144 + 262144)

typedef _Float16 h8 __attribute__((ext_vector_type(8)));
typedef float    f4 __attribute__((ext_vector_type(4)));

__device__ __forceinline__ int C2i(int x){ return x*(x-1)/2; }
__device__ __forceinline__ int C3i(int x){ return x*(x-1)*(x-2)/6; }

#define MT 64

// ======== stage 0: zero accumulators + weight conversion to f16 (one dispatch) ========
__global__ __launch_bounds__(256) void k_cvt(const float* __restrict__ W1,
    const float* __restrict__ Wl, const float* __restrict__ Wr,
    _Float16* __restrict__ hbase, float* __restrict__ ws){
  int i = blockIdx.x*256 + threadIdx.x;
  if (i < ZERO_FLOATS) ws[i] = 0.f;
  if (i < 16384){
    float x = W1[i];
    _Float16 h = (_Float16)x;
    hbase[HOFF_W1H + i] = h;
    hbase[HOFF_W1L + i] = (_Float16)(x - (float)h);
  }
  int j = i - 16384;
  if (j >= 0 && j < 262144) hbase[HOFF_WLH + j] = (_Float16)Wl[j];
  int k2 = i - (16384 + 262144);
  if (k2 >= 0 && k2 < 262144) hbase[HOFF_WRH + k2] = (_Float16)Wr[k2];
}

// ================= stage A: z=relu(X@W1^T+b1); LN; logit=zn.W2+b2 =================
// MFMA 16x16x32 f16, 2-way hi/lo split for f32-grade precision. No LDS/barriers.
__global__ __launch_bounds__(256) void k_logits(const float* __restrict__ X,
    const _Float16* __restrict__ W1h, const _Float16* __restrict__ W1l,
    const float* __restrict__ b1, const float* __restrict__ ln_g,
    const float* __restrict__ ln_b, const float* __restrict__ W2,
    const float* __restrict__ b2, float* __restrict__ logits){
  int t = threadIdx.x;
  int w = t >> 6;
  int lane = t & 63;
  int l15 = lane & 15, quad = lane >> 4;
  int base = blockIdx.x * MT;
  int mA = base + 16*w + l15;

  const float* xrow = X + (size_t)mA*HH;
  h8 ah[4], al[4];
  #pragma unroll
  for (int c=0;c<4;++c){
    float4 u = *(const float4*)(xrow + c*32 + quad*8);
    float4 v = *(const float4*)(xrow + c*32 + quad*8 + 4);
    float xv[8] = {u.x,u.y,u.z,u.w,v.x,v.y,v.z,v.w};
    #pragma unroll
    for (int j=0;j<8;++j){
      _Float16 hi = (_Float16)xv[j];
      ah[c][j] = hi;
      al[c][j] = (_Float16)(xv[j] - (float)hi);
    }
  }

  f4 acc[8];
  #pragma unroll
  for (int nt=0;nt<8;++nt) acc[nt] = (f4){0.f,0.f,0.f,0.f};

  #pragma unroll
  for (int c=0;c<4;++c){
    #pragma unroll
    for (int nt=0;nt<8;++nt){
      int o = nt*16 + l15;
      h8 bh  = *(const h8*)(W1h + (size_t)o*HH + c*32 + quad*8);
      h8 bl_ = *(const h8*)(W1l + (size_t)o*HH + c*32 + quad*8);
      acc[nt] = __builtin_amdgcn_mfma_f32_16x16x32_f16(ah[c], bh,  acc[nt], 0,0,0);
      acc[nt] = __builtin_amdgcn_mfma_f32_16x16x32_f16(al[c], bh,  acc[nt], 0,0,0);
      acc[nt] = __builtin_amdgcn_mfma_f32_16x16x32_f16(ah[c], bl_, acc[nt], 0,0,0);
      acc[nt] = __builtin_amdgcn_mfma_f32_16x16x32_f16(al[c], bl_, acc[nt], 0,0,0);
    }
  }

  float bv[8], gv[8], lv[8], wv[8];
  #pragma unroll
  for (int nt=0;nt<8;++nt){
    int o = nt*16 + l15;
    bv[nt]=b1[o]; gv[nt]=ln_g[o]; lv[nt]=ln_b[o]; wv[nt]=W2[o];
  }
  float b2v = b2[0];
  #pragma unroll
  for (int r=0;r<4;++r){
    float z[8];
    float s1=0.f, s2=0.f;
    #pragma unroll
    for (int nt=0;nt<8;++nt){
      float zz = acc[nt][r] + bv[nt];
      zz = zz>0.f ? zz : 0.f;
      z[nt] = zz; s1 += zz; s2 += zz*zz;
    }
    #pragma unroll
    for (int m=1;m<16;m<<=1){ s1 += __shfl_xor(s1,m); s2 += __shfl_xor(s2,m); }
    float mu = s1/(float)HH;
    float var = s2/(float)HH - mu*mu;
    float rs = 1.0f/sqrtf(var+EPSF);
    float s3 = 0.f;
    #pragma unroll
    for (int nt=0;nt<8;++nt){
      float zn = (z[nt]-mu)*rs*gv[nt] + lv[nt];
      s3 += zn*wv[nt];
    }
    #pragma unroll
    for (int m=1;m<16;m<<=1) s3 += __shfl_xor(s3,m);
    if (l15 == 0) logits[base + 16*w + quad*4 + r] = s3 + b2v;
  }
}

// ================= stage B: softmax fi, top-4, class ranks, node lists =================
__global__ __launch_bounds__(256) void k_topk(const float* __restrict__ logits,
    int* __restrict__ cols, int* __restrict__ ranks, float* __restrict__ fiSel,
    int* __restrict__ nodeCnt, int* __restrict__ nodeList){
  __shared__ int lcnt[CCC];
  __shared__ int lbase[CCC];
  int t = threadIdx.x;
  if (t < CCC) lcnt[t] = 0;
  __syncthreads();
  int n = blockIdx.x*256 + t;
  float l[CCC];
  #pragma unroll
  for (int c=0;c<CCC;++c) l[c] = logits[n*CCC+c];
  unsigned mask = 0;
  #pragma unroll
  for (int k=0;k<KTOP;++k){
    float best = -3e38f; int bi = 0;
    #pragma unroll
    for (int c=0;c<CCC;++c){
      bool taken = (mask>>c)&1u;
      if (!taken && l[c] > best){ best = l[c]; bi = c; }
    }
    mask |= 1u<<bi;
  }
  float m = -3e38f;
  #pragma unroll
  for (int c=0;c<CCC;++c) m = l[c]>m ? l[c] : m;
  float s = 0.f;
  #pragma unroll
  for (int c=0;c<CCC;++c) s += expf(l[c]-m);
  float inv = 1.0f/s;
  int mycis[KTOP], mypos[KTOP];
  unsigned m2 = mask;
  for (int j=0;j<KTOP;++j){
    int ci = __ffs(m2)-1; m2 &= m2-1u;
    unsigned rest = mask & ~(1u<<ci);
    int v[3]; unsigned r2 = rest;
    #pragma unroll
    for (int q=0;q<3;++q){ int col = __ffs(r2)-1; r2 &= r2-1u; v[q] = col - (col>ci ? 1:0); }
    int rank = C3i(v[2]) + C2i(v[1]) + v[0];
    int e4 = n*KTOP + j;
    cols[e4] = ci; ranks[e4] = rank;
    fiSel[e4] = expf(l[ci]-m)*inv;
    mycis[j] = ci;
    mypos[j] = atomicAdd(&lcnt[ci], 1);
  }
  __syncthreads();
  if (t < CCC) lbase[t] = atomicAdd(&nodeCnt[t*16], lcnt[t]);
  __syncthreads();
  #pragma unroll
  for (int j=0;j<KTOP;++j){
    int ci = mycis[j];
    nodeList[ci*NN + lbase[ci] + mypos[j]] = n*KTOP + j;
  }
}

// ================= stage C: class feature sums (global atomics, 6144 blocks) ==========
__global__ __launch_bounds__(256) void k_accF(const float* __restrict__ X,
    const int* __restrict__ cols, const int* __restrict__ ranks,
    const float* __restrict__ fiSel, float* __restrict__ F, float* __restrict__ cnt){
  int e = blockIdx.x*2 + (threadIdx.x>>7);
  int h = threadIdx.x & 127;
  int ci = cols[e], rank = ranks[e];
  float fi = fiSel[e];
  int n = e >> 2;
  float v = X[(n*CCC+ci)*HH + h] * fi;
  atomicAdd(&F[(ci*NCLS+rank)*HH + h], v);
  if (h==0) atomicAdd(&cnt[ci*NCLS+rank], 1.0f);
}

// ====== stage D (fused): pairs + singles + degrees + inclusion-exclusion agg ======
// grid (8 col-blocks of 16, 16 ci), 256 thr. P/U in LDS; one dispatch replaces 3.
__global__ __launch_bounds__(256) void k_graph(const float* __restrict__ F,
    const float* __restrict__ cnt, float* __restrict__ agg){
  int cb = blockIdx.x, ci = blockIdx.y, t = threadIdx.x;
  __shared__ float cntl[NCLS];
  __shared__ float PcS[105], UcS[15];
  __shared__ int   abcs[NCLS];   // a | b<<5 | c<<10
  __shared__ int   prs[NCLS];    // pab | pac<<10 | pbc<<20
  __shared__ float P[105*16];
  __shared__ float U[15*16];
  const float* Fc = F + (size_t)ci*NCLS*HH + cb*16;

  for (int r=t; r<NCLS; r+=256){
    cntl[r] = cnt[ci*NCLS+r];
    int c=2; while (c<14 && C3i(c+1)<=r) c++;
    int rem = r - C3i(c);
    int b=1; while (b<c-1 && C2i(b+1)<=rem) b++;
    int a = rem - C2i(b);
    abcs[r] = a | (b<<5) | (c<<10);
    prs[r] = (C2i(b)+a) | ((C2i(c)+a)<<10) | ((C2i(c)+b)<<20);
  }
  __syncthreads();
  if (t<105){
    int pb=1; while (pb<14 && C2i(pb+1)<=t) pb++;
    int pa = t - C2i(pb);
    float s=0.f;
    #pragma unroll
    for (int z=0;z<15;++z){
      if (z==pa||z==pb) continue;
      int lo,mid,hi;
      if (z<pa){lo=z;mid=pa;hi=pb;} else if (z<pb){lo=pa;mid=z;hi=pb;} else {lo=pa;mid=pb;hi=z;}
      s += cntl[C3i(hi)+C2i(mid)+lo];
    }
    PcS[t]=s;
  }
  __syncthreads();
  if (t<15){
    float s=0.f;
    #pragma unroll
    for (int y=0;y<15;++y){
      if (y==t) continue;
      int lo = t<y?t:y, hi = t<y?y:t;
      s += PcS[C2i(hi)+lo];
    }
    UcS[t]=0.5f*s;
  }
  __syncthreads();
  // vector pair sums
  for (int idx=t; idx<105*16; idx+=256){
    int p = idx>>4, col = idx&15;
    int pb=1; while (pb<14 && C2i(pb+1)<=p) pb++;
    int pa = p - C2i(pb);
    float s=0.f;
    #pragma unroll
    for (int z=0;z<15;++z){
      if (z==pa||z==pb) continue;
      int lo,mid,hi;
      if (z<pa){lo=z;mid=pa;hi=pb;} else if (z<pb){lo=pa;mid=z;hi=pb;} else {lo=pa;mid=pb;hi=z;}
      s += Fc[(size_t)(C3i(hi)+C2i(mid)+lo)*HH + col];
    }
    P[idx]=s;
  }
  __syncthreads();
  // vector singles
  for (int idx=t; idx<15*16; idx+=256){
    int x = idx>>4, col = idx&15;
    float s=0.f;
    #pragma unroll
    for (int y=0;y<15;++y){
      if (y==x) continue;
      int lo = x<y?x:y, hi = x<y?y:x;
      s += P[(C2i(hi)+lo)*16 + col];
    }
    U[idx]=0.5f*s;
  }
  __syncthreads();
  // agg via inclusion-exclusion
  for (int idx=t; idx<NCLS*16; idx+=256){
    int r = idx>>4, col = idx&15;
    int v1=abcs[r]; int a=v1&31,b=(v1>>5)&31,c=(v1>>10)&31;
    int v2=prs[r];  int pab=v2&1023,pac=(v2>>10)&1023,pbc=(v2>>20)&1023;
    float deg = UcS[a]+UcS[b]+UcS[c]-PcS[pab]-PcS[pac]-PcS[pbc]+cntl[r];
    float invd = 1.0f/fmaxf(deg,1.0f);
    float v = U[a*16+col]+U[b*16+col]+U[c*16+col]
            - P[pab*16+col]-P[pac*16+col]-P[pbc*16+col]
            + Fc[(size_t)r*HH + col];
    agg[(size_t)ci*NCLS*HH + (size_t)r*HH + cb*16 + col] = v*invd;
  }
}

// ================= stage E1: AggWl = Agg @ Wl^T + bl (per class, in-place, f16 MFMA) ====
__global__ __launch_bounds__(256) void k_aggwl(float* __restrict__ agg,
    const _Float16* __restrict__ Wlh, const float* __restrict__ bl){
  int t = threadIdx.x;
  int w = t >> 6;
  int lane = t & 63;
  int l15 = lane & 15, quad = lane >> 4;
  int ci = blockIdx.y;
  int base = blockIdx.x * MT;
  int rowA = base + 16*w + l15; if (rowA > NCLS-1) rowA = NCLS-1;

  const float* arow = agg + ((size_t)ci*NCLS + rowA)*HH;
  h8 af[4];
  #pragma unroll
  for (int c=0;c<4;++c){
    float4 u = *(const float4*)(arow + c*32 + quad*8);
    float4 v = *(const float4*)(arow + c*32 + quad*8 + 4);
    float xv[8] = {u.x,u.y,u.z,u.w,v.x,v.y,v.z,v.w};
    #pragma unroll
    for (int j=0;j<8;++j) af[c][j] = (_Float16)xv[j];
  }

  f4 acc[8];
  #pragma unroll
  for (int nt=0;nt<8;++nt) acc[nt] = (f4){0.f,0.f,0.f,0.f};

  const _Float16* Wc = Wlh + (size_t)ci*HH*HH;
  #pragma unroll
  for (int c=0;c<4;++c){
    #pragma unroll
    for (int nt=0;nt<8;++nt){
      int o = nt*16 + l15;
      h8 bh = *(const h8*)(Wc + (size_t)o*HH + c*32 + quad*8);
      acc[nt] = __builtin_amdgcn_mfma_f32_16x16x32_f16(af[c], bh, acc[nt], 0,0,0);
    }
  }
  #pragma unroll
  for (int r=0;r<4;++r){
    int row2 = base + 16*w + quad*4 + r;
    if (row2 < NCLS){
      float* drow = agg + ((size_t)ci*NCLS + row2)*HH;
      #pragma unroll
      for (int nt=0;nt<8;++nt){
        int o = nt*16 + l15;
        drow[o] = acc[nt][r] + bl[ci*HH + o];
      }
    }
  }
}

// ================= stage E2: hc = relu(AggWl[class] + fi*X @ Wr^T) (f16 MFMA) =========
__global__ __launch_bounds__(256) void k_hc2(const float* __restrict__ X,
    const _Float16* __restrict__ Wrh,
    const int* __restrict__ ranks, const float* __restrict__ fiSel,
    const int* __restrict__ nodeCnt, const int* __restrict__ nodeList,
    const float* __restrict__ aggwl, float* __restrict__ hcBuf, float* __restrict__ sums){
  int ci = blockIdx.y;
  int cntc = nodeCnt[ci*16];
  int base = blockIdx.x * MT;
  if (base >= cntc) return;
  __shared__ float rb[8];
  int t = threadIdx.x;
  int w = t >> 6;
  int lane = t & 63;
  int l15 = lane & 15, quad = lane >> 4;

  int pA = base + 16*w + l15;
  float fi = 0.f; int nA = 0;
  if (pA < cntc){
    int e = nodeList[ci*NN + pA];
    fi = fiSel[e]; nA = e >> 2;
  }
  const float* xrow = X + ((size_t)nA*CCC + ci)*HH;
  h8 af[4];
  #pragma unroll
  for (int c=0;c<4;++c){
    float4 u = *(const float4*)(xrow + c*32 + quad*8);
    float4 v = *(const float4*)(xrow + c*32 + quad*8 + 4);
    float xv[8] = {u.x,u.y,u.z,u.w,v.x,v.y,v.z,v.w};
    #pragma unroll
    for (int j=0;j<8;++j) af[c][j] = (_Float16)(xv[j]*fi);
  }

  f4 acc[8];
  #pragma unroll
  for (int nt=0;nt<8;++nt) acc[nt] = (f4){0.f,0.f,0.f,0.f};

  const _Float16* Wc = Wrh + (size_t)ci*HH*HH;
  #pragma unroll
  for (int c=0;c<4;++c){
    #pragma unroll
    for (int nt=0;nt<8;++nt){
      int o = nt*16 + l15;
      h8 bh = *(const h8*)(Wc + (size_t)o*HH + c*32 + quad*8);
      acc[nt] = __builtin_amdgcn_mfma_f32_16x16x32_f16(af[c], bh, acc[nt], 0,0,0);
    }
  }

  float s1 = 0.f, s2 = 0.f;
  #pragma unroll
  for (int r=0;r<4;++r){
    int pD = base + 16*w + quad*4 + r;
    int e2 = -1, rk2 = 0;
    if (pD < cntc){ e2 = nodeList[ci*NN + pD]; rk2 = ranks[e2]; }
    if (e2 >= 0){
      const float* G = aggwl + ((size_t)ci*NCLS + rk2)*HH;
      float* drow = hcBuf + (size_t)e2*HH;
      #pragma unroll
      for (int nt=0;nt<8;++nt){
        int o = nt*16 + l15;
        float vv = acc[nt][r] + G[o];
        vv = vv>0.f ? vv : 0.f;
        drow[o] = vv;
        s1 += vv; s2 += vv*vv;
      }
    }
  }
  #pragma unroll
  for (int m=1;m<64;m<<=1){ s1 += __shfl_xor(s1,m); s2 += __shfl_xor(s2,m); }
  if (lane == 0){ rb[w] = s1; rb[4+w] = s2; }
  __syncthreads();
  if (t==0){
    atomicAdd(&sums[ci],    rb[0]+rb[1]+rb[2]+rb[3]);
    atomicAdd(&sums[16+ci], rb[4]+rb[5]+rb[6]+rb[7]);
  }
}

// ================= stage F: masked mean/var normalize, write output =================
__global__ __launch_bounds__(256) void k_out(const float* __restrict__ hcBuf,
    const int* __restrict__ cols, const int* __restrict__ nodeCnt,
    const float* __restrict__ sums, float* __restrict__ out){
  int idx = blockIdx.x*256 + threadIdx.x;
  int e = idx >> 7;
  int ci = cols[e];
  float cntf = (float)nodeCnt[ci*16];
  float nel = fmaxf(cntf * (float)HH, 1.0f);
  float mu = sums[ci]/nel;
  float var = sums[16+ci]/nel - mu*mu;
  out[idx] = (hcBuf[idx]-mu)/sqrtf(var+EPSF);
}

extern "C" void kernel_launch(void* const* d_in, const int* in_sizes, int n_in,
                              void* d_out, int out_size, void* d_ws, size_t ws_size,
                              hipStream_t stream){
  const float* X    = (const float*)d_in[0];
  const float* W1   = (const float*)d_in[1];
  const float* b1   = (const float*)d_in[2];
  const float* ln_g = (const float*)d_in[3];
  const float* ln_b = (const float*)d_in[4];
  const float* W2   = (const float*)d_in[5];
  const float* b2   = (const float*)d_in[6];
  const float* Wl   = (const float*)d_in[7];
  const float* bl   = (const float*)d_in[8];
  const float* Wr   = (const float*)d_in[9];
  float* ws = (float*)d_ws;
  float* F      = ws + OFF_F;
  float* cnt    = ws + OFF_CNT;
  float* sums   = ws + OFF_SUMS;
  int*   nodeCnt= (int*)(ws + OFF_NCNT);
  float* logits = ws + OFF_LOGITS;
  int*   cols   = (int*)(ws + OFF_COLS);
  int*   ranks  = (int*)(ws + OFF_RANKS);
  float* fiSel  = ws + OFF_FISEL;
  int*   nodeList=(int*)(ws + OFF_NLIST);
  float* agg    = ws + OFF_AGG;
  float* hcBuf  = ws + OFF_HC;
  _Float16* hbase = (_Float16*)(ws + OFF_HALF);
  float* out    = (float*)d_out;

  // k_cvt zeroes F/cnt/sums/nodeCnt (ZERO_FLOATS) AND converts weights.
  int cvtGrid = (ZERO_FLOATS > CVT_TOTAL ? ZERO_FLOATS : CVT_TOTAL + 255) / 256 + 1;
  k_cvt    <<<dim3(cvtGrid), dim3(256), 0, stream>>>(W1, Wl, Wr, hbase, ws);
  k_logits <<<dim3(NN*CCC/MT), dim3(256), 0, stream>>>(X, hbase+HOFF_W1H, hbase+HOFF_W1L,
                                                       b1, ln_g, ln_b, W2, b2, logits);
  k_topk   <<<dim3(NN/256), dim3(256), 0, stream>>>(logits, cols, ranks, fiSel, nodeCnt, nodeList);
  k_accF   <<<dim3(NN*KTOP/2), dim3(256), 0, stream>>>(X, cols, ranks, fiSel, F, cnt);
  k_graph  <<<dim3(8,16), dim3(256), 0, stream>>>(F, cnt, agg);
  k_aggwl  <<<dim3((NCLS+MT-1)/MT,16), dim3(256), 0, stream>>>(agg, hbase+HOFF_WLH, bl);
  k_hc2    <<<dim3((NN/MT),16), dim3(256), 0, stream>>>(X, hbase+HOFF_WRH, ranks, fiSel,
                                                        nodeCnt, nodeList, agg, hcBuf, sums);
  k_out    <<<dim3(NN*KTOP*HH/256), dim3(256), 0, stream>>>(hcBuf, cols, nodeCnt, sums, out);
}